// Round 4
// baseline (1512.382 us; speedup 1.0000x reference)
//
#include <hip/hip_runtime.h>
#include <cstdint>

// ---------------- common ----------------
#define NROW 131072   // B*K

typedef short bf16x8 __attribute__((ext_vector_type(8)));
typedef float f32x4 __attribute__((ext_vector_type(4)));

__device__ __forceinline__ unsigned short f2bf(float f){
  unsigned u = __builtin_bit_cast(unsigned, f);
  u += 0x7fffu + ((u >> 16) & 1u);
  return (unsigned short)(u >> 16);
}
__device__ __forceinline__ float bf2f(unsigned v){
  unsigned u = v << 16; return __builtin_bit_cast(float, u);
}
__device__ __forceinline__ float sigf(float x){ return 1.0f/(1.0f + __expf(-x)); }
__device__ __forceinline__ float tanh_fast(float x){ return 2.0f/(1.0f + __expf(-2.0f*x)) - 1.0f; }

// ---------- workspace layout (byte offsets) ----------
// XOA  [0x00000000, 0x06000000)  131072 x 384 bf16 [Of|Or|A]  (96 MiB)
// Y2   [0x06000000, 0x0E000000)  131072 x 512 bf16            (128 MiB)
// SM   [0x0E000000, 0x0E390000)  small region
// Ys   [0x0E390000, 0x0F390000)  4096 x 1024 fp32 (16 MiB)
#define WS_XOA  0x00000000UL
#define WS_Y2   0x06000000UL
#define WS_SM   0x0E000000UL
#define WS_YS   0x0E390000UL
#define NEED2   0x0F390000UL   // proven to fit in round 2
// small-region offsets (relative to WS_SM)
#define SM_W1F  0x000000       // W1 frag layout, 2 MiB
#define SM_W2F  0x200000       // W2 frag layout, 1 MiB
#define SM_WIH  0x300000
#define SM_WHH  0x340000
#define SM_BIAS 0x380000
#define SM_STAT 0x381000
#define SM_A1   0x384000
#define SM_C1   0x385000
#define SM_A2   0x386000
#define SM_C2   0x386800

// ---------------- prep: frag-layout weight conversion ----------------
// lstm frag (N=512,K=128): element j of slot ((nt*4+kt)*64+lane)
//   = W[nt*16+(lane&15)][kt*32+(lane>>4)*8+j]
__device__ __forceinline__ void conv_frag(const float* __restrict__ src, unsigned short* __restrict__ dst,
                                          long g, long T){
  for (long i = g; i < 8192; i += T){
    int lane = (int)(i & 63);
    int blk  = (int)(i >> 6);
    int nt = blk >> 2, kt = blk & 3;
    const float* sp = src + (nt*16 + (lane&15))*128 + kt*32 + (lane>>4)*8;
    float4 a = *(const float4*)sp;
    float4 b = *(const float4*)(sp+4);
    uint4 o;
    o.x = (unsigned)f2bf(a.x) | ((unsigned)f2bf(a.y) << 16);
    o.y = (unsigned)f2bf(a.z) | ((unsigned)f2bf(a.w) << 16);
    o.z = (unsigned)f2bf(b.x) | ((unsigned)f2bf(b.y) << 16);
    o.w = (unsigned)f2bf(b.z) | ((unsigned)f2bf(b.w) << 16);
    *((uint4*)dst + i) = o;
  }
}

// W1f: slot = (((chunk*16 + kb)*2 + ksub)*8 + c16)*64 + lane ; elem j =
//   W1[chunk*128 + c16*16 + (lane&15)][kb*64 + ksub*32 + (lane>>4)*8 + j]
// W2f: slot = (((nt*2 + kh)*2 + ksub)*32 + c16)*64 + lane ; elem j =
//   W2[c16*16 + (lane&15)][nt*128 + kh*64 + ksub*32 + (lane>>4)*8 + j]
__global__ __launch_bounds__(256) void prep_kernel(
    const float* __restrict__ wihf, const float* __restrict__ whhf,
    const float* __restrict__ bihf, const float* __restrict__ bhhf,
    const float* __restrict__ wihr, const float* __restrict__ whhr,
    const float* __restrict__ bihr, const float* __restrict__ bhhr,
    const float* __restrict__ W1, const float* __restrict__ W2,
    unsigned short* __restrict__ W1f, unsigned short* __restrict__ W2f,
    unsigned short* __restrict__ wih, unsigned short* __restrict__ whh,
    float* __restrict__ bias){
  const long T = (long)gridDim.x * 256;
  const long g = (long)blockIdx.x * 256 + threadIdx.x;
  for (long s = g; s < 131072; s += T){
    int lane = (int)(s & 63);
    long t = s >> 6;
    int c16 = (int)(t & 7);
    long t2 = t >> 3;
    int ksub = (int)(t2 & 1);
    long t3 = t2 >> 1;
    int kb = (int)(t3 & 15);
    int chunk = (int)(t3 >> 4);
    const float* sp = W1 + (long)(chunk*128 + c16*16 + (lane&15))*1024 + kb*64 + ksub*32 + (lane>>4)*8;
    float4 a = *(const float4*)sp;
    float4 b = *(const float4*)(sp+4);
    uint4 o;
    o.x = (unsigned)f2bf(a.x) | ((unsigned)f2bf(a.y) << 16);
    o.y = (unsigned)f2bf(a.z) | ((unsigned)f2bf(a.w) << 16);
    o.z = (unsigned)f2bf(b.x) | ((unsigned)f2bf(b.y) << 16);
    o.w = (unsigned)f2bf(b.z) | ((unsigned)f2bf(b.w) << 16);
    *((uint4*)W1f + s) = o;
  }
  for (long s = g; s < 65536; s += T){
    int lane = (int)(s & 63);
    long t = s >> 6;
    int c16 = (int)(t & 31);
    long t2 = t >> 5;
    int ksub = (int)(t2 & 1);
    long t3 = t2 >> 1;
    int kh = (int)(t3 & 1);
    int nt = (int)(t3 >> 1);
    const float* sp = W2 + (long)(c16*16 + (lane&15))*1024 + nt*128 + kh*64 + ksub*32 + (lane>>4)*8;
    float4 a = *(const float4*)sp;
    float4 b = *(const float4*)(sp+4);
    uint4 o;
    o.x = (unsigned)f2bf(a.x) | ((unsigned)f2bf(a.y) << 16);
    o.y = (unsigned)f2bf(a.z) | ((unsigned)f2bf(a.w) << 16);
    o.z = (unsigned)f2bf(b.x) | ((unsigned)f2bf(b.y) << 16);
    o.w = (unsigned)f2bf(b.z) | ((unsigned)f2bf(b.w) << 16);
    *((uint4*)W2f + s) = o;
  }
  conv_frag(wihf, wih, g, T);
  conv_frag(whhf, whh, g, T);
  conv_frag(wihr, wih + 65536, g, T);
  conv_frag(whhr, whh + 65536, g, T);
  for (long i = g; i < 512; i += T){
    bias[i]       = bihf[i] + bhhf[i];
    bias[512 + i] = bihr[i] + bhhr[i];
  }
}

// ---------------- reg = sum mean(p^2) ----------------
__global__ __launch_bounds__(256) void reg_kernel(
    const float* p0, const float* p1, const float* p2, const float* p3,
    const float* p4, const float* p5, const float* p6, const float* p7,
    const float* p8, const float* p9, const float* p10, const float* p11,
    const float* p12, const float* p13, const float* p14, const float* p15,
    const float* p16, const float* p17, float* __restrict__ out){
  const int tid = threadIdx.x;
  const long T = (long)gridDim.x * 256;
  const long g = (long)blockIdx.x * 256 + tid;
  float local = 0.f;
#define RLOOP(P, SZ) for (long i = g; i < (SZ); i += T){ float v = (P)[i]; local += v*v*(1.0f/(float)(SZ)); }
  RLOOP(p0, 65536) RLOOP(p1, 65536) RLOOP(p2, 512) RLOOP(p3, 512)
  RLOOP(p4, 65536) RLOOP(p5, 65536) RLOOP(p6, 512) RLOOP(p7, 512)
  RLOOP(p8, 1048576) RLOOP(p9, 1024) RLOOP(p10, 1024) RLOOP(p11, 1024)
  RLOOP(p12, 524288) RLOOP(p13, 512) RLOOP(p14, 512) RLOOP(p15, 512)
  RLOOP(p16, 512) RLOOP(p17, 1)
#undef RLOOP
  #pragma unroll
  for (int off=32; off>=1; off>>=1) local += __shfl_down(local, off);
  __shared__ float wsum[4];
  if ((tid & 63) == 0) wsum[tid>>6] = local;
  __syncthreads();
  if (tid == 0) atomicAdd(out, wsum[0]+wsum[1]+wsum[2]+wsum[3]);
}

// ---------------- BiLSTM (unchanged, proven) ----------------
__global__ __launch_bounds__(256, 1) void lstm_kernel(
    const float* __restrict__ action,
    const unsigned short* __restrict__ wih_all,
    const unsigned short* __restrict__ whh_all,
    const float* __restrict__ bias_all,
    unsigned short* __restrict__ XOA){
  const int dir = blockIdx.y;
  const int b0 = blockIdx.x * 32;
  const unsigned short* __restrict__ wih = wih_all + dir * 65536;
  const unsigned short* __restrict__ whh = whh_all + dir * 65536;
  const float* __restrict__ bias = bias_all + dir * 512;
  __shared__ __align__(16) unsigned short lh[32*136];
  const int tid = threadIdx.x;
  const int lane = tid & 63;
  const int wv = tid >> 6;
  const int l15 = lane & 15, l4 = lane >> 4;
  for (int i = tid; i < 32*136; i += 256) lh[i] = 0;
  float bias_r[2][4];
  #pragma unroll
  for (int qq=0;qq<2;qq++)
    #pragma unroll
    for (int G2=0;G2<4;G2++)
      bias_r[qq][G2] = bias[G2*128 + (2*wv+qq)*16 + l15];
  f32x4 cst[2][2];
  #pragma unroll
  for (int mt=0;mt<2;mt++)
    #pragma unroll
    for (int qq=0;qq<2;qq++){ f32x4 z = {0.f,0.f,0.f,0.f}; cst[mt][qq] = z; }
  __syncthreads();

  for (int s = 0; s < 32; s++){
    const int korig = dir ? (31 - s) : s;
    bf16x8 ha[2][4];
    #pragma unroll
    for (int mt=0;mt<2;mt++)
      #pragma unroll
      for (int kt=0;kt<4;kt++)
        ha[mt][kt] = *(const bf16x8*)&lh[(mt*16 + l15)*136 + kt*32 + l4*8];
    __syncthreads();
    bf16x8 xa[2][4];
    #pragma unroll
    for (int mt=0;mt<2;mt++)
      #pragma unroll
      for (int kt=0;kt<4;kt++){
        const float* sp = action + ((long)(b0 + mt*16 + l15)*32 + korig)*128 + kt*32 + l4*8;
        float4 a = *(const float4*)sp;
        float4 b = *(const float4*)(sp + 4);
        bf16x8 t;
        t[0]=(short)f2bf(a.x); t[1]=(short)f2bf(a.y); t[2]=(short)f2bf(a.z); t[3]=(short)f2bf(a.w);
        t[4]=(short)f2bf(b.x); t[5]=(short)f2bf(b.y); t[6]=(short)f2bf(b.z); t[7]=(short)f2bf(b.w);
        xa[mt][kt] = t;
      }
    f32x4 acc[2][2][4];
    #pragma unroll
    for (int mt=0;mt<2;mt++)
      #pragma unroll
      for (int qq=0;qq<2;qq++)
        #pragma unroll
        for (int G2=0;G2<4;G2++){
          float bb = bias_r[qq][G2];
          f32x4 z = {bb,bb,bb,bb};
          acc[mt][qq][G2] = z;
        }
    #pragma unroll
    for (int G2=0;G2<4;G2++)
      #pragma unroll
      for (int qq=0;qq<2;qq++){
        const int nt = G2*8 + 2*wv + qq;
        #pragma unroll
        for (int kt=0;kt<4;kt++){
          bf16x8 bw = *(const bf16x8*)&wih[((nt*4 + kt)*64 + lane)*8];
          acc[0][qq][G2] = __builtin_amdgcn_mfma_f32_16x16x32_bf16(xa[0][kt], bw, acc[0][qq][G2], 0,0,0);
          acc[1][qq][G2] = __builtin_amdgcn_mfma_f32_16x16x32_bf16(xa[1][kt], bw, acc[1][qq][G2], 0,0,0);
        }
        #pragma unroll
        for (int kt=0;kt<4;kt++){
          bf16x8 bw = *(const bf16x8*)&whh[((nt*4 + kt)*64 + lane)*8];
          acc[0][qq][G2] = __builtin_amdgcn_mfma_f32_16x16x32_bf16(ha[0][kt], bw, acc[0][qq][G2], 0,0,0);
          acc[1][qq][G2] = __builtin_amdgcn_mfma_f32_16x16x32_bf16(ha[1][kt], bw, acc[1][qq][G2], 0,0,0);
        }
      }
    #pragma unroll
    for (int mt=0;mt<2;mt++)
      #pragma unroll
      for (int qq=0;qq<2;qq++){
        const int hcol = (2*wv+qq)*16 + l15;
        #pragma unroll
        for (int r=0;r<4;r++){
          float iv = acc[mt][qq][0][r];
          float fv = acc[mt][qq][1][r];
          float gv = acc[mt][qq][2][r];
          float ov = acc[mt][qq][3][r];
          float c = cst[mt][qq][r];
          c = sigf(fv)*c + sigf(iv)*tanh_fast(gv);
          float h = sigf(ov)*tanh_fast(c);
          cst[mt][qq][r] = c;
          const int row = mt*16 + l4*4 + r;
          unsigned short hb = f2bf(h);
          lh[row*136 + hcol] = hb;
          XOA[((long)(b0+row)*32 + korig)*384 + dir*128 + hcol] = hb;
        }
      }
    __syncthreads();
  }
}

// ---------------- attention (unchanged) ----------------
__global__ __launch_bounds__(256) void attn_pack(
    const float* __restrict__ action,
    unsigned short* __restrict__ XOA){
  const int b = blockIdx.x;
  const int tid = threadIdx.x;
  __shared__ __align__(16) float V[32][132];
  __shared__ __align__(16) float attw[32][33];
  const float* __restrict__ src = action + (long)b*32*128;
  for (int i = tid; i < 1024; i += 256){
    int r = i >> 5, c4 = i & 31;
    *(float4*)&V[r][c4*4] = *(const float4*)&src[r*128 + c4*4];
  }
  __syncthreads();
  const int i = tid >> 3, j0 = tid & 7;
  float sacc[4] = {0.f,0.f,0.f,0.f};
  for (int c=0;c<32;c++){
    float4 vi = *(const float4*)&V[i][c*4];
    #pragma unroll
    for (int jj=0;jj<4;jj++){
      float4 vj = *(const float4*)&V[j0 + jj*8][c*4];
      sacc[jj] += vi.x*vj.x + vi.y*vj.y + vi.z*vj.z + vi.w*vj.w;
    }
  }
  float m = fmaxf(fmaxf(sacc[0],sacc[1]), fmaxf(sacc[2],sacc[3]));
  #pragma unroll
  for (int off=1; off<8; off<<=1) m = fmaxf(m, __shfl_xor(m, off));
  float e0 = __expf(sacc[0]-m), e1 = __expf(sacc[1]-m), e2 = __expf(sacc[2]-m), e3 = __expf(sacc[3]-m);
  float ssum = e0+e1+e2+e3;
  #pragma unroll
  for (int off=1; off<8; off<<=1) ssum += __shfl_xor(ssum, off);
  float inv = 1.0f / ssum;
  attw[i][j0] = e0*inv; attw[i][j0+8] = e1*inv; attw[i][j0+16] = e2*inv; attw[i][j0+24] = e3*inv;
  __syncthreads();
  const int d0 = (tid & 7) * 16;
  float a[16];
  #pragma unroll
  for (int t=0;t<16;t++) a[t]=0.f;
  for (int j=0;j<32;j++){
    float w = attw[i][j];
    #pragma unroll
    for (int dd=0;dd<4;dd++){
      float4 v = *(const float4*)&V[j][d0 + dd*4];
      a[dd*4+0] += w*v.x; a[dd*4+1] += w*v.y; a[dd*4+2] += w*v.z; a[dd*4+3] += w*v.w;
    }
  }
  unsigned short* rowp = XOA + ((long)b*32 + i)*384;
  #pragma unroll
  for (int t=0;t<8;t++){
    ushort2 u; u.x = f2bf(a[t*2]); u.y = f2bf(a[t*2+1]);
    *(ushort2*)(rowp + 256 + d0 + t*2) = u;
  }
}

// ---------------- Ys = state @ W1[:, 0:512]^T  (state-broadcast trick) ----------------
// 4096 x 1024 fp32. K = 512 (kb 0..7). MFMA accumulation order identical to the
// unsplit chain → downstream results bitwise identical.
__global__ __launch_bounds__(256, 3) void ys_kernel(
    const float* __restrict__ state,
    const unsigned short* __restrict__ W1f,
    float* __restrict__ Ys){
  __shared__ __align__(16) unsigned short lA[2][8192];
  const int tid = threadIdx.x;
  const int lane = tid & 63;
  const long m0 = (long)blockIdx.x * 128;   // state row
  const int chunk = blockIdx.y;             // n-chunk of 128
  const int mh = (tid >> 6) >> 1, nh = (tid >> 6) & 1;
  f32x4 acc[4][4];
  #pragma unroll
  for (int a=0;a<4;a++)
    #pragma unroll
    for (int b=0;b<4;b++){ f32x4 z = {0.f,0.f,0.f,0.f}; acc[a][b] = z; }

  bf16x8 sa[4];
  const int srow = tid >> 3;
  const int sg   = (tid & 7) * 8;

  auto load_g = [&](int kb){
    const int k0 = kb << 6;
    #pragma unroll
    for (int i=0;i<4;i++){
      long r = m0 + i*32 + srow;
      const float* sp = state + r*512 + k0 + sg;
      float4 a = *(const float4*)sp;
      float4 b = *(const float4*)(sp + 4);
      bf16x8 t;
      t[0]=(short)f2bf(a.x); t[1]=(short)f2bf(a.y); t[2]=(short)f2bf(a.z); t[3]=(short)f2bf(a.w);
      t[4]=(short)f2bf(b.x); t[5]=(short)f2bf(b.y); t[6]=(short)f2bf(b.z); t[7]=(short)f2bf(b.w);
      sa[i] = t;
    }
  };
  auto write_l = [&](int buf){
    #pragma unroll
    for (int i=0;i<4;i++){
      int r = i*32 + srow;
      int j = ((tid&7) ^ (r & 7)) * 8;
      *(bf16x8*)&lA[buf][r*64 + j] = sa[i];
    }
  };
  auto compute = [&](int buf, int kb){
    #pragma unroll
    for (int ksub=0; ksub<2; ksub++){
      const unsigned short* wb = W1f + (((chunk*16 + kb)*2 + ksub)*8 + nh*4)*512 + lane*8;
      bf16x8 af[4], bg[4];
      #pragma unroll
      for (int nt=0;nt<4;nt++) bg[nt] = *(const bf16x8*)(wb + nt*512);
      #pragma unroll
      for (int mt=0;mt<4;mt++){
        int r = mh*64 + mt*16 + (lane&15);
        int p = (ksub*4 + (lane>>4)) ^ (r&7);
        af[mt] = *(const bf16x8*)&lA[buf][r*64 + p*8];
      }
      #pragma unroll
      for (int mt=0;mt<4;mt++)
        #pragma unroll
        for (int nt=0;nt<4;nt++)
          acc[mt][nt] = __builtin_amdgcn_mfma_f32_16x16x32_bf16(af[mt], bg[nt], acc[mt][nt], 0,0,0);
    }
  };

  load_g(0);
  write_l(0);
  __syncthreads();
  for (int kb = 0; kb < 8; kb++){
    if (kb + 1 < 8) load_g(kb+1);
    compute(kb & 1, kb);
    if (kb + 1 < 8) write_l((kb+1) & 1);
    __syncthreads();
  }

  #pragma unroll
  for (int nt=0; nt<4; nt++){
    int col = chunk*128 + nh*64 + nt*16 + (lane & 15);
    #pragma unroll
    for (int mt=0; mt<4; mt++){
      #pragma unroll
      for (int r=0;r<4;r++){
        long row = m0 + mh*64 + mt*16 + (lane>>4)*4 + r;
        Ys[row*1024 + col] = acc[mt][nt][r];
      }
    }
  }
}

// ---------------- pass 1: GEMM1-z stats, X-resident ----------------
// 64-row blocks. Stage the X z-half (64x512 bf16, XOR-swizzled, 64 KB) ONCE,
// then loop over 8 n-chunks; acc init from Ys.
// Wave tiling: 1x4 col split (wave w owns 64 rows x 32 cols) — each W1f
// fragment read by exactly ONE wave (halves L2 weight traffic vs 2x2).
// MFMA K-order per output element unchanged → bitwise identical.
__global__ __launch_bounds__(256, 2) void gemm1_stats(
    const float* __restrict__ action,
    const unsigned short* __restrict__ XOA,
    const unsigned short* __restrict__ W1f,
    const float* __restrict__ Ys,
    float* __restrict__ bnsum, float* __restrict__ bnsq){
  __shared__ __align__(16) unsigned short stage[4][8192];  // kbp 4..7
  const int tid = threadIdx.x;
  const int lane = tid & 63;
  const int w = tid >> 6;                   // col-group of 32 within 128-chunk
  const long m0 = (long)blockIdx.x * 64;

  // ---- stage X z-half once ----
  #pragma unroll
  for (int kbp = 4; kbp < 8; kbp++){
    #pragma unroll
    for (int i=0;i<4;i++){
      int ch = i*256 + tid;
      int row = ch >> 4, kc = ch & 15;
      long R = m0 + row;
      bf16x8 t;
      if (kbp == 6){
        const float* sp = action + R*128 + kc*8;
        float4 a = *(const float4*)sp;
        float4 b = *(const float4*)(sp + 4);
        t[0]=(short)f2bf(a.x); t[1]=(short)f2bf(a.y); t[2]=(short)f2bf(a.z); t[3]=(short)f2bf(a.w);
        t[4]=(short)f2bf(b.x); t[5]=(short)f2bf(b.y); t[6]=(short)f2bf(b.z); t[7]=(short)f2bf(b.w);
      } else {
        int col = (kbp < 6) ? ((kbp-4)*128) : 256;
        t = *(const bf16x8*)&XOA[R*384 + col + kc*8];
      }
      int j = (kc ^ (row & 7)) * 8;
      *(bf16x8*)&stage[kbp-4][row*128 + j] = t;
    }
  }
  __syncthreads();

  const long rbb = m0 >> 5;   // first state row of this block
  for (int chunk = 0; chunk < 8; chunk++){
    f32x4 acc[4][2];
    #pragma unroll
    for (int rt=0;rt<4;rt++){
      long rb = rbb + (rt >> 1);
      #pragma unroll
      for (int ct=0;ct<2;ct++){
        int col = chunk*128 + w*32 + ct*16 + (lane & 15);
        float v = Ys[rb*1024 + col];
        f32x4 z = {v,v,v,v}; acc[rt][ct] = z;
      }
    }
    #pragma unroll
    for (int kbp=4; kbp<8; kbp++){
      #pragma unroll
      for (int ks4=0; ks4<4; ks4++){
        const int kb = kbp*2 + (ks4 >> 1);
        const int ksub = ks4 & 1;
        const unsigned short* wb = W1f + (((chunk*16 + kb)*2 + ksub)*8 + w*2)*512 + lane*8;
        bf16x8 af[4], bg[2];
        #pragma unroll
        for (int ct=0;ct<2;ct++) bg[ct] = *(const bf16x8*)(wb + ct*512);
        #pragma unroll
        for (int rt=0;rt<4;rt++){
          int r = rt*16 + (lane&15);
          int p = (ks4*4 + (lane>>4)) ^ (r&7);
          af[rt] = *(const bf16x8*)&stage[kbp-4][r*128 + p*8];
        }
        #pragma unroll
        for (int rt=0;rt<4;rt++)
          #pragma unroll
          for (int ct=0;ct<2;ct++)
            acc[rt][ct] = __builtin_amdgcn_mfma_f32_16x16x32_bf16(af[rt], bg[ct], acc[rt][ct], 0,0,0);
      }
    }
    // stats epilogue for this chunk
    #pragma unroll
    for (int ct=0;ct<2;ct++){
      int col = chunk*128 + w*32 + ct*16 + (lane & 15);
      float s = 0.f, q = 0.f;
      #pragma unroll
      for (int rt=0;rt<4;rt++)
        #pragma unroll
        for (int r=0;r<4;r++){
          float v = acc[rt][ct][r];
          s += v; q += v*v;
        }
      s += __shfl_down(s, 32); q += __shfl_down(q, 32);
      s += __shfl_down(s, 16); q += __shfl_down(q, 16);
      if (lane < 16){
        atomicAdd(&bnsum[col], s);
        atomicAdd(&bnsq[col], q);
      }
    }
  }
}

// ---------------- BN finalize ----------------
__global__ void bn_finalize(const float* __restrict__ sum, const float* __restrict__ sq,
                            const float* __restrict__ gamma, const float* __restrict__ beta,
                            float* __restrict__ a, float* __restrict__ c, int N){
  int i = blockIdx.x*256 + threadIdx.x;
  if (i >= N) return;
  const float invM = 1.0f / 131072.0f;
  float mu = sum[i]*invM;
  float var = sq[i]*invM - mu*mu;
  float s = rsqrtf(var + 1e-5f) * gamma[i];
  a[i] = s;
  c[i] = beta[i] - mu*s;
}

// ---------------- pass 2: fused GEMM1-z recompute -> BN1+ReLU -> GEMM2 ----------------
// X-resident; wave tiling 1x4 col split in BOTH phases (wave owns 64 rows x
// 32 cols in phase A, 64 rows x 128 cols in phase B) — weight fragments read
// by exactly one wave (halves L2 weight stream + VMEM instr count).
__global__ __launch_bounds__(256, 2) void gemm12(
    const float* __restrict__ action,
    const unsigned short* __restrict__ XOA,
    const unsigned short* __restrict__ W1f,
    const unsigned short* __restrict__ W2f,
    const float* __restrict__ Ys,
    const float* __restrict__ a1, const float* __restrict__ c1,
    unsigned short* __restrict__ Y2,
    float* __restrict__ bnsum, float* __restrict__ bnsq){
  __shared__ __align__(16) unsigned short stage[4][8192];  // X z-half, kbp 4..7
  __shared__ __align__(16) unsigned short h1c[8192];       // 64x128, XOR-swizzled
  const int tid = threadIdx.x;
  const int lane = tid & 63;
  const int w = tid >> 6;
  const long m0 = (long)blockIdx.x * 64;

  // ---- stage X z-half once ----
  #pragma unroll
  for (int kbp = 4; kbp < 8; kbp++){
    #pragma unroll
    for (int i=0;i<4;i++){
      int ch = i*256 + tid;
      int row = ch >> 4, kc = ch & 15;
      long R = m0 + row;
      bf16x8 t;
      if (kbp == 6){
        const float* sp = action + R*128 + kc*8;
        float4 a = *(const float4*)sp;
        float4 b = *(const float4*)(sp + 4);
        t[0]=(short)f2bf(a.x); t[1]=(short)f2bf(a.y); t[2]=(short)f2bf(a.z); t[3]=(short)f2bf(a.w);
        t[4]=(short)f2bf(b.x); t[5]=(short)f2bf(b.y); t[6]=(short)f2bf(b.z); t[7]=(short)f2bf(b.w);
      } else {
        int col = (kbp < 6) ? ((kbp-4)*128) : 256;
        t = *(const bf16x8*)&XOA[R*384 + col + kc*8];
      }
      int j = (kc ^ (row & 7)) * 8;
      *(bf16x8*)&stage[kbp-4][row*128 + j] = t;
    }
  }

  f32x4 acc2[4][8];
  #pragma unroll
  for (int a=0;a<4;a++)
    #pragma unroll
    for (int b=0;b<8;b++){ f32x4 z = {0.f,0.f,0.f,0.f}; acc2[a][b] = z; }

  const long rbb = m0 >> 5;
  __syncthreads();   // stage ready

  for (int nt = 0; nt < 8; nt++){
    // ---- phase A: acc1 = Ys + X_z @ W1_z^T (chunk nt); wave w: cols w*32..w*32+31 ----
    f32x4 acc1[4][2];
    #pragma unroll
    for (int rt=0;rt<4;rt++){
      long rb = rbb + (rt >> 1);
      #pragma unroll
      for (int ct=0;ct<2;ct++){
        int col = nt*128 + w*32 + ct*16 + (lane & 15);
        float v = Ys[rb*1024 + col];
        f32x4 z = {v,v,v,v}; acc1[rt][ct] = z;
      }
    }
    #pragma unroll
    for (int kbp=4; kbp<8; kbp++){
      #pragma unroll
      for (int ks4=0; ks4<4; ks4++){
        const int kb = kbp*2 + (ks4 >> 1);
        const int ksub = ks4 & 1;
        const unsigned short* wb = W1f + (((nt*16 + kb)*2 + ksub)*8 + w*2)*512 + lane*8;
        bf16x8 af[4], bg[2];
        #pragma unroll
        for (int ct=0;ct<2;ct++) bg[ct] = *(const bf16x8*)(wb + ct*512);
        #pragma unroll
        for (int rt=0;rt<4;rt++){
          int r = rt*16 + (lane&15);
          int p = (ks4*4 + (lane>>4)) ^ (r&7);
          af[rt] = *(const bf16x8*)&stage[kbp-4][r*128 + p*8];
        }
        #pragma unroll
        for (int rt=0;rt<4;rt++)
          #pragma unroll
          for (int ct=0;ct<2;ct++)
            acc1[rt][ct] = __builtin_amdgcn_mfma_f32_16x16x32_bf16(af[rt], bg[ct], acc1[rt][ct], 0,0,0);
      }
    }

    __syncthreads();   // prev nt's phase-B h1c reads complete

    // ---- BN1 + relu -> h1c (XOR-swizzled) ----
    #pragma unroll
    for (int ct=0;ct<2;ct++){
      int lcol = w*32 + ct*16 + (lane&15);
      float av = a1[nt*128 + lcol];
      float cv = c1[nt*128 + lcol];
      #pragma unroll
      for (int rt=0;rt<4;rt++)
        #pragma unroll
        for (int r=0;r<4;r++){
          int row = rt*16 + (lane>>4)*4 + r;
          float h = fmaxf(fmaf(acc1[rt][ct][r], av, cv), 0.f);
          int sc = (lcol & 7) | ((((lcol >> 3) ^ (row & 7)) & 15) << 3);
          h1c[row*128 + sc] = f2bf(h);
        }
    }
    __syncthreads();   // h1c ready

    // ---- phase B: acc2 += h1c @ W2^T ; wave w: cols w*128..w*128+127 ----
    #pragma unroll
    for (int kh=0;kh<2;kh++){
      #pragma unroll
      for (int ksub=0;ksub<2;ksub++){
        bf16x8 af[4];
        #pragma unroll
        for (int rt=0;rt<4;rt++){
          int row = rt*16 + (lane&15);
          int g0 = kh*8 + ksub*4 + (lane>>4);
          int gs = g0 ^ (row & 7);
          af[rt] = *(const bf16x8*)&h1c[row*128 + gs*8];
        }
        const unsigned short* wb = W2f + ((((nt*2 + kh)*2 + ksub)*32) + w*8)*512 + lane*8;
        bf16x8 bg[8];
        #pragma unroll
        for (int ct=0;ct<8;ct++) bg[ct] = *(const bf16x8*)(wb + ct*512);
        #pragma unroll
        for (int rt=0;rt<4;rt++)
          #pragma unroll
          for (int ct=0;ct<8;ct++)
            acc2[rt][ct] = __builtin_amdgcn_mfma_f32_16x16x32_bf16(af[rt], bg[ct], acc2[rt][ct], 0,0,0);
      }
    }
    // no barrier here: next nt's first barrier orders h1c reads vs rewrite
  }

  // epilogue: Y2 bf16 store + BN2 stats (wave w owns cols w*128..w*128+127)
  #pragma unroll
  for (int ct=0;ct<8;ct++){
    int col = w*128 + ct*16 + (lane&15);
    float s = 0.f, q = 0.f;
    #pragma unroll
    for (int rt=0;rt<4;rt++)
      #pragma unroll
      for (int r=0;r<4;r++){
        long row = m0 + rt*16 + (lane>>4)*4 + r;
        unsigned short ub = f2bf(acc2[rt][ct][r]);
        Y2[row*512 + col] = ub;
        float vq = bf2f(ub);
        s += vq; q += vq*vq;
      }
    s += __shfl_down(s, 32); q += __shfl_down(q, 32);
    s += __shfl_down(s, 16); q += __shfl_down(q, 16);
    if (lane < 16){
      atomicAdd(&bnsum[col], s);
      atomicAdd(&bnsq[col], q);
    }
  }
}

// ---------------- layer3 ----------------
__global__ __launch_bounds__(256) void final_kernel(
    const unsigned short* __restrict__ Y2,
    const float* __restrict__ a2, const float* __restrict__ c2,
    const float* __restrict__ W3, const float* __restrict__ b3, float* __restrict__ Q){
  const int tid = threadIdx.x;
  const int lane = tid & 63, wv = tid >> 6;
  const int wid = blockIdx.x*4 + wv;
  const int cb = lane*8;
  float4 a0 = *(const float4*)&a2[cb], a1 = *(const float4*)&a2[cb+4];
  float4 c0 = *(const float4*)&c2[cb], c1 = *(const float4*)&c2[cb+4];
  float4 w0 = *(const float4*)&W3[cb], w1 = *(const float4*)&W3[cb+4];
  const float b3v = b3[0];
  for (long row = wid; row < NROW; row += 4096){
    uint4 u = *(const uint4*)(Y2 + row*512 + cb);
    float y0 = bf2f(u.x & 0xffffu), y1 = bf2f(u.x >> 16);
    float y2 = bf2f(u.y & 0xffffu), y3 = bf2f(u.y >> 16);
    float y4 = bf2f(u.z & 0xffffu), y5 = bf2f(u.z >> 16);
    float y6 = bf2f(u.w & 0xffffu), y7 = bf2f(u.w >> 16);
    float t = fmaxf(fmaf(y0,a0.x,c0.x),0.f)*w0.x
            + fmaxf(fmaf(y1,a0.y,c0.y),0.f)*w0.y
            + fmaxf(fmaf(y2,a0.z,c0.z),0.f)*w0.z
            + fmaxf(fmaf(y3,a0.w,c0.w),0.f)*w0.w
            + fmaxf(fmaf(y4,a1.x,c1.x),0.f)*w1.x
            + fmaxf(fmaf(y5,a1.y,c1.y),0.f)*w1.y
            + fmaxf(fmaf(y6,a1.z,c1.z),0.f)*w1.z
            + fmaxf(fmaf(y7,a1.w,c1.w),0.f)*w1.w;
    #pragma unroll
    for (int off=32; off>=1; off>>=1) t += __shfl_down(t, off);
    if (lane == 0) Q[row] = t + b3v;
  }
}

// ---------------- launch ----------------
extern "C" void kernel_launch(void* const* d_in, const int* in_sizes, int n_in,
                              void* d_out, int out_size, void* d_ws, size_t ws_size,
                              hipStream_t stream){
  (void)in_sizes; (void)n_in; (void)out_size;
  if (ws_size < NEED2) return;   // proven to fit in round 2

  const float* state  = (const float*)d_in[0];
  const float* action = (const float*)d_in[1];
  const float* w_ih_f = (const float*)d_in[2];
  const float* w_hh_f = (const float*)d_in[3];
  const float* b_ih_f = (const float*)d_in[4];
  const float* b_hh_f = (const float*)d_in[5];
  const float* w_ih_r = (const float*)d_in[6];
  const float* w_hh_r = (const float*)d_in[7];
  const float* b_ih_r = (const float*)d_in[8];
  const float* b_hh_r = (const float*)d_in[9];
  const float* W1  = (const float*)d_in[10];
  const float* b1  = (const float*)d_in[11];
  const float* g1  = (const float*)d_in[12];
  const float* be1 = (const float*)d_in[13];
  const float* W2  = (const float*)d_in[14];
  const float* b2  = (const float*)d_in[15];
  const float* g2  = (const float*)d_in[16];
  const float* be2 = (const float*)d_in[17];
  const float* W3  = (const float*)d_in[18];
  const float* b3  = (const float*)d_in[19];
  (void)b1; (void)b2;  // cancel inside BatchNorm

  char* ws = (char*)d_ws;
  unsigned short* XOA = (unsigned short*)(ws + WS_XOA);
  unsigned short* Y2  = (unsigned short*)(ws + WS_Y2);
  float* Ysp = (float*)(ws + WS_YS);
  char* sm = ws + WS_SM;
  unsigned short* W1f = (unsigned short*)(sm + SM_W1F);
  unsigned short* W2f = (unsigned short*)(sm + SM_W2F);
  unsigned short* wih = (unsigned short*)(sm + SM_WIH);
  unsigned short* whh = (unsigned short*)(sm + SM_WHH);
  float* bias   = (float*)(sm + SM_BIAS);
  float* bnsum1 = (float*)(sm + SM_STAT);
  float* bnsq1  = (float*)(sm + SM_STAT + 0x1000);
  float* bnsum2 = (float*)(sm + SM_STAT + 0x2000);
  float* bnsq2  = (float*)(sm + SM_STAT + 0x2800);
  float* a1 = (float*)(sm + SM_A1);
  float* c1 = (float*)(sm + SM_C1);
  float* a2 = (float*)(sm + SM_A2);
  float* c2 = (float*)(sm + SM_C2);
  float* qout = (float*)d_out;
  float* regout = qout + 131072;

  hipMemsetAsync(bnsum1, 0, 0x3000, stream);
  hipMemsetAsync(regout, 0, 4, stream);

  prep_kernel<<<1024, 256, 0, stream>>>(w_ih_f, w_hh_f, b_ih_f, b_hh_f,
                                        w_ih_r, w_hh_r, b_ih_r, b_hh_r,
                                        W1, W2, W1f, W2f, wih, whh, bias);
  reg_kernel<<<256, 256, 0, stream>>>(w_ih_f, w_hh_f, b_ih_f, b_hh_f,
                                      w_ih_r, w_hh_r, b_ih_r, b_hh_r,
                                      W1, b1, g1, be1, W2, b2, g2, be2, W3, b3, regout);
  ys_kernel<<<dim3(32, 8), 256, 0, stream>>>(state, W1f, Ysp);
  lstm_kernel<<<dim3(128,2), 256, 0, stream>>>(action, wih, whh, bias, XOA);
  attn_pack<<<4096, 256, 0, stream>>>(action, XOA);
  gemm1_stats<<<2048, 256, 0, stream>>>(action, XOA, W1f, Ysp, bnsum1, bnsq1);
  bn_finalize<<<4, 256, 0, stream>>>(bnsum1, bnsq1, g1, be1, a1, c1, 1024);
  gemm12<<<2048, 256, 0, stream>>>(action, XOA, W1f, W2f, Ysp, a1, c1, Y2, bnsum2, bnsq2);
  bn_finalize<<<2, 256, 0, stream>>>(bnsum2, bnsq2, g2, be2, a2, c2, 512);
  final_kernel<<<1024, 256, 0, stream>>>(Y2, a2, c2, W3, b3, qout);
}

// Round 5
// 1496.817 us; speedup vs baseline: 1.0104x; 1.0104x over previous
//
#include <hip/hip_runtime.h>
#include <cstdint>

// ---------------- common ----------------
#define NROW 131072   // B*K

typedef short bf16x8 __attribute__((ext_vector_type(8)));
typedef float f32x4 __attribute__((ext_vector_type(4)));

__device__ __forceinline__ unsigned short f2bf(float f){
  unsigned u = __builtin_bit_cast(unsigned, f);
  u += 0x7fffu + ((u >> 16) & 1u);
  return (unsigned short)(u >> 16);
}
__device__ __forceinline__ float bf2f(unsigned v){
  unsigned u = v << 16; return __builtin_bit_cast(float, u);
}
__device__ __forceinline__ float sigf(float x){ return 1.0f/(1.0f + __expf(-x)); }
__device__ __forceinline__ float tanh_fast(float x){ return 2.0f/(1.0f + __expf(-2.0f*x)) - 1.0f; }

// ---------- workspace layout (byte offsets) ----------
// XOA  [0x00000000, 0x06000000)  131072 x 384 bf16 [Of|Or|A]  (96 MiB)
// Y2   [0x06000000, 0x0E000000)  131072 x 512 bf16            (128 MiB)
// SM   [0x0E000000, 0x0E390000)  small region
// Ys   [0x0E390000, 0x0F390000)  4096 x 1024 fp32 (16 MiB)
#define WS_XOA  0x00000000UL
#define WS_Y2   0x06000000UL
#define WS_SM   0x0E000000UL
#define WS_YS   0x0E390000UL
#define NEED2   0x0F390000UL   // proven to fit in round 2
// small-region offsets (relative to WS_SM)
#define SM_W1F  0x000000       // W1 frag layout, 2 MiB
#define SM_W2F  0x200000       // W2 frag layout, 1 MiB
#define SM_WIH  0x300000
#define SM_WHH  0x340000
#define SM_BIAS 0x380000
#define SM_STAT 0x381000
#define SM_A1   0x384000
#define SM_C1   0x385000
#define SM_A2   0x386000
#define SM_C2   0x386800

// ---------------- prep: frag-layout weight conversion ----------------
// lstm frag (N=512,K=128): element j of slot ((nt*4+kt)*64+lane)
//   = W[nt*16+(lane&15)][kt*32+(lane>>4)*8+j]
__device__ __forceinline__ void conv_frag(const float* __restrict__ src, unsigned short* __restrict__ dst,
                                          long g, long T){
  for (long i = g; i < 8192; i += T){
    int lane = (int)(i & 63);
    int blk  = (int)(i >> 6);
    int nt = blk >> 2, kt = blk & 3;
    const float* sp = src + (nt*16 + (lane&15))*128 + kt*32 + (lane>>4)*8;
    float4 a = *(const float4*)sp;
    float4 b = *(const float4*)(sp+4);
    uint4 o;
    o.x = (unsigned)f2bf(a.x) | ((unsigned)f2bf(a.y) << 16);
    o.y = (unsigned)f2bf(a.z) | ((unsigned)f2bf(a.w) << 16);
    o.z = (unsigned)f2bf(b.x) | ((unsigned)f2bf(b.y) << 16);
    o.w = (unsigned)f2bf(b.z) | ((unsigned)f2bf(b.w) << 16);
    *((uint4*)dst + i) = o;
  }
}

// W1f: slot = (((chunk*16 + kb)*2 + ksub)*8 + c16)*64 + lane ; elem j =
//   W1[chunk*128 + c16*16 + (lane&15)][kb*64 + ksub*32 + (lane>>4)*8 + j]
// W2f: slot = (((nt*2 + kh)*2 + ksub)*32 + c16)*64 + lane ; elem j =
//   W2[c16*16 + (lane&15)][nt*128 + kh*64 + ksub*32 + (lane>>4)*8 + j]
__global__ __launch_bounds__(256) void prep_kernel(
    const float* __restrict__ wihf, const float* __restrict__ whhf,
    const float* __restrict__ bihf, const float* __restrict__ bhhf,
    const float* __restrict__ wihr, const float* __restrict__ whhr,
    const float* __restrict__ bihr, const float* __restrict__ bhhr,
    const float* __restrict__ W1, const float* __restrict__ W2,
    unsigned short* __restrict__ W1f, unsigned short* __restrict__ W2f,
    unsigned short* __restrict__ wih, unsigned short* __restrict__ whh,
    float* __restrict__ bias){
  const long T = (long)gridDim.x * 256;
  const long g = (long)blockIdx.x * 256 + threadIdx.x;
  for (long s = g; s < 131072; s += T){
    int lane = (int)(s & 63);
    long t = s >> 6;
    int c16 = (int)(t & 7);
    long t2 = t >> 3;
    int ksub = (int)(t2 & 1);
    long t3 = t2 >> 1;
    int kb = (int)(t3 & 15);
    int chunk = (int)(t3 >> 4);
    const float* sp = W1 + (long)(chunk*128 + c16*16 + (lane&15))*1024 + kb*64 + ksub*32 + (lane>>4)*8;
    float4 a = *(const float4*)sp;
    float4 b = *(const float4*)(sp+4);
    uint4 o;
    o.x = (unsigned)f2bf(a.x) | ((unsigned)f2bf(a.y) << 16);
    o.y = (unsigned)f2bf(a.z) | ((unsigned)f2bf(a.w) << 16);
    o.z = (unsigned)f2bf(b.x) | ((unsigned)f2bf(b.y) << 16);
    o.w = (unsigned)f2bf(b.z) | ((unsigned)f2bf(b.w) << 16);
    *((uint4*)W1f + s) = o;
  }
  for (long s = g; s < 65536; s += T){
    int lane = (int)(s & 63);
    long t = s >> 6;
    int c16 = (int)(t & 31);
    long t2 = t >> 5;
    int ksub = (int)(t2 & 1);
    long t3 = t2 >> 1;
    int kh = (int)(t3 & 1);
    int nt = (int)(t3 >> 1);
    const float* sp = W2 + (long)(c16*16 + (lane&15))*1024 + nt*128 + kh*64 + ksub*32 + (lane>>4)*8;
    float4 a = *(const float4*)sp;
    float4 b = *(const float4*)(sp+4);
    uint4 o;
    o.x = (unsigned)f2bf(a.x) | ((unsigned)f2bf(a.y) << 16);
    o.y = (unsigned)f2bf(a.z) | ((unsigned)f2bf(a.w) << 16);
    o.z = (unsigned)f2bf(b.x) | ((unsigned)f2bf(b.y) << 16);
    o.w = (unsigned)f2bf(b.z) | ((unsigned)f2bf(b.w) << 16);
    *((uint4*)W2f + s) = o;
  }
  conv_frag(wihf, wih, g, T);
  conv_frag(whhf, whh, g, T);
  conv_frag(wihr, wih + 65536, g, T);
  conv_frag(whhr, whh + 65536, g, T);
  for (long i = g; i < 512; i += T){
    bias[i]       = bihf[i] + bhhf[i];
    bias[512 + i] = bihr[i] + bhhr[i];
  }
}

// ---------------- reg = sum mean(p^2) ----------------
__global__ __launch_bounds__(256) void reg_kernel(
    const float* p0, const float* p1, const float* p2, const float* p3,
    const float* p4, const float* p5, const float* p6, const float* p7,
    const float* p8, const float* p9, const float* p10, const float* p11,
    const float* p12, const float* p13, const float* p14, const float* p15,
    const float* p16, const float* p17, float* __restrict__ out){
  const int tid = threadIdx.x;
  const long T = (long)gridDim.x * 256;
  const long g = (long)blockIdx.x * 256 + tid;
  float local = 0.f;
#define RLOOP(P, SZ) for (long i = g; i < (SZ); i += T){ float v = (P)[i]; local += v*v*(1.0f/(float)(SZ)); }
  RLOOP(p0, 65536) RLOOP(p1, 65536) RLOOP(p2, 512) RLOOP(p3, 512)
  RLOOP(p4, 65536) RLOOP(p5, 65536) RLOOP(p6, 512) RLOOP(p7, 512)
  RLOOP(p8, 1048576) RLOOP(p9, 1024) RLOOP(p10, 1024) RLOOP(p11, 1024)
  RLOOP(p12, 524288) RLOOP(p13, 512) RLOOP(p14, 512) RLOOP(p15, 512)
  RLOOP(p16, 512) RLOOP(p17, 1)
#undef RLOOP
  #pragma unroll
  for (int off=32; off>=1; off>>=1) local += __shfl_down(local, off);
  __shared__ float wsum[4];
  if ((tid & 63) == 0) wsum[tid>>6] = local;
  __syncthreads();
  if (tid == 0) atomicAdd(out, wsum[0]+wsum[1]+wsum[2]+wsum[3]);
}

// ---------------- BiLSTM: 16 rows/block (2 blocks/CU for latency hiding) ----------------
// Same MFMA K-order per output element as the 32-row version -> bitwise identical h.
__global__ __launch_bounds__(256, 2) void lstm_kernel(
    const float* __restrict__ action,
    const unsigned short* __restrict__ wih_all,
    const unsigned short* __restrict__ whh_all,
    const float* __restrict__ bias_all,
    unsigned short* __restrict__ XOA){
  const int dir = blockIdx.y;
  const int b0 = blockIdx.x * 16;
  const unsigned short* __restrict__ wih = wih_all + dir * 65536;
  const unsigned short* __restrict__ whh = whh_all + dir * 65536;
  const float* __restrict__ bias = bias_all + dir * 512;
  __shared__ __align__(16) unsigned short lh[16*136];
  const int tid = threadIdx.x;
  const int lane = tid & 63;
  const int wv = tid >> 6;
  const int l15 = lane & 15, l4 = lane >> 4;
  for (int i = tid; i < 16*136; i += 256) lh[i] = 0;
  float bias_r[2][4];
  #pragma unroll
  for (int qq=0;qq<2;qq++)
    #pragma unroll
    for (int G2=0;G2<4;G2++)
      bias_r[qq][G2] = bias[G2*128 + (2*wv+qq)*16 + l15];
  f32x4 cst[2];
  #pragma unroll
  for (int qq=0;qq<2;qq++){ f32x4 z = {0.f,0.f,0.f,0.f}; cst[qq] = z; }
  __syncthreads();

  for (int s = 0; s < 32; s++){
    const int korig = dir ? (31 - s) : s;
    bf16x8 ha[4];
    #pragma unroll
    for (int kt=0;kt<4;kt++)
      ha[kt] = *(const bf16x8*)&lh[l15*136 + kt*32 + l4*8];
    __syncthreads();
    bf16x8 xa[4];
    #pragma unroll
    for (int kt=0;kt<4;kt++){
      const float* sp = action + ((long)(b0 + l15)*32 + korig)*128 + kt*32 + l4*8;
      float4 a = *(const float4*)sp;
      float4 b = *(const float4*)(sp + 4);
      bf16x8 t;
      t[0]=(short)f2bf(a.x); t[1]=(short)f2bf(a.y); t[2]=(short)f2bf(a.z); t[3]=(short)f2bf(a.w);
      t[4]=(short)f2bf(b.x); t[5]=(short)f2bf(b.y); t[6]=(short)f2bf(b.z); t[7]=(short)f2bf(b.w);
      xa[kt] = t;
    }
    f32x4 acc[2][4];
    #pragma unroll
    for (int qq=0;qq<2;qq++)
      #pragma unroll
      for (int G2=0;G2<4;G2++){
        float bb = bias_r[qq][G2];
        f32x4 z = {bb,bb,bb,bb};
        acc[qq][G2] = z;
      }
    #pragma unroll
    for (int G2=0;G2<4;G2++)
      #pragma unroll
      for (int qq=0;qq<2;qq++){
        const int nt = G2*8 + 2*wv + qq;
        #pragma unroll
        for (int kt=0;kt<4;kt++){
          bf16x8 bw = *(const bf16x8*)&wih[((nt*4 + kt)*64 + lane)*8];
          acc[qq][G2] = __builtin_amdgcn_mfma_f32_16x16x32_bf16(xa[kt], bw, acc[qq][G2], 0,0,0);
        }
        #pragma unroll
        for (int kt=0;kt<4;kt++){
          bf16x8 bw = *(const bf16x8*)&whh[((nt*4 + kt)*64 + lane)*8];
          acc[qq][G2] = __builtin_amdgcn_mfma_f32_16x16x32_bf16(ha[kt], bw, acc[qq][G2], 0,0,0);
        }
      }
    #pragma unroll
    for (int qq=0;qq<2;qq++){
      const int hcol = (2*wv+qq)*16 + l15;
      #pragma unroll
      for (int r=0;r<4;r++){
        float iv = acc[qq][0][r];
        float fv = acc[qq][1][r];
        float gv = acc[qq][2][r];
        float ov = acc[qq][3][r];
        float c = cst[qq][r];
        c = sigf(fv)*c + sigf(iv)*tanh_fast(gv);
        float h = sigf(ov)*tanh_fast(c);
        cst[qq][r] = c;
        const int row = l4*4 + r;
        unsigned short hb = f2bf(h);
        lh[row*136 + hcol] = hb;
        XOA[((long)(b0+row)*32 + korig)*384 + dir*128 + hcol] = hb;
      }
    }
    __syncthreads();
  }
}

// ---------------- attention (unchanged) ----------------
__global__ __launch_bounds__(256) void attn_pack(
    const float* __restrict__ action,
    unsigned short* __restrict__ XOA){
  const int b = blockIdx.x;
  const int tid = threadIdx.x;
  __shared__ __align__(16) float V[32][132];
  __shared__ __align__(16) float attw[32][33];
  const float* __restrict__ src = action + (long)b*32*128;
  for (int i = tid; i < 1024; i += 256){
    int r = i >> 5, c4 = i & 31;
    *(float4*)&V[r][c4*4] = *(const float4*)&src[r*128 + c4*4];
  }
  __syncthreads();
  const int i = tid >> 3, j0 = tid & 7;
  float sacc[4] = {0.f,0.f,0.f,0.f};
  for (int c=0;c<32;c++){
    float4 vi = *(const float4*)&V[i][c*4];
    #pragma unroll
    for (int jj=0;jj<4;jj++){
      float4 vj = *(const float4*)&V[j0 + jj*8][c*4];
      sacc[jj] += vi.x*vj.x + vi.y*vj.y + vi.z*vj.z + vi.w*vj.w;
    }
  }
  float m = fmaxf(fmaxf(sacc[0],sacc[1]), fmaxf(sacc[2],sacc[3]));
  #pragma unroll
  for (int off=1; off<8; off<<=1) m = fmaxf(m, __shfl_xor(m, off));
  float e0 = __expf(sacc[0]-m), e1 = __expf(sacc[1]-m), e2 = __expf(sacc[2]-m), e3 = __expf(sacc[3]-m);
  float ssum = e0+e1+e2+e3;
  #pragma unroll
  for (int off=1; off<8; off<<=1) ssum += __shfl_xor(ssum, off);
  float inv = 1.0f / ssum;
  attw[i][j0] = e0*inv; attw[i][j0+8] = e1*inv; attw[i][j0+16] = e2*inv; attw[i][j0+24] = e3*inv;
  __syncthreads();
  const int d0 = (tid & 7) * 16;
  float a[16];
  #pragma unroll
  for (int t=0;t<16;t++) a[t]=0.f;
  for (int j=0;j<32;j++){
    float w = attw[i][j];
    #pragma unroll
    for (int dd=0;dd<4;dd++){
      float4 v = *(const float4*)&V[j][d0 + dd*4];
      a[dd*4+0] += w*v.x; a[dd*4+1] += w*v.y; a[dd*4+2] += w*v.z; a[dd*4+3] += w*v.w;
    }
  }
  unsigned short* rowp = XOA + ((long)b*32 + i)*384;
  #pragma unroll
  for (int t=0;t<8;t++){
    ushort2 u; u.x = f2bf(a[t*2]); u.y = f2bf(a[t*2+1]);
    *(ushort2*)(rowp + 256 + d0 + t*2) = u;
  }
}

// ---------------- Ys = state @ W1[:, 0:512]^T  (state-broadcast trick) ----------------
// 4096 x 1024 fp32. K = 512 (kb 0..7). MFMA accumulation order identical to the
// unsplit chain → downstream results bitwise identical.
__global__ __launch_bounds__(256, 3) void ys_kernel(
    const float* __restrict__ state,
    const unsigned short* __restrict__ W1f,
    float* __restrict__ Ys){
  __shared__ __align__(16) unsigned short lA[2][8192];
  const int tid = threadIdx.x;
  const int lane = tid & 63;
  const long m0 = (long)blockIdx.x * 128;   // state row
  const int chunk = blockIdx.y;             // n-chunk of 128
  const int mh = (tid >> 6) >> 1, nh = (tid >> 6) & 1;
  f32x4 acc[4][4];
  #pragma unroll
  for (int a=0;a<4;a++)
    #pragma unroll
    for (int b=0;b<4;b++){ f32x4 z = {0.f,0.f,0.f,0.f}; acc[a][b] = z; }

  bf16x8 sa[4];
  const int srow = tid >> 3;
  const int sg   = (tid & 7) * 8;

  auto load_g = [&](int kb){
    const int k0 = kb << 6;
    #pragma unroll
    for (int i=0;i<4;i++){
      long r = m0 + i*32 + srow;
      const float* sp = state + r*512 + k0 + sg;
      float4 a = *(const float4*)sp;
      float4 b = *(const float4*)(sp + 4);
      bf16x8 t;
      t[0]=(short)f2bf(a.x); t[1]=(short)f2bf(a.y); t[2]=(short)f2bf(a.z); t[3]=(short)f2bf(a.w);
      t[4]=(short)f2bf(b.x); t[5]=(short)f2bf(b.y); t[6]=(short)f2bf(b.z); t[7]=(short)f2bf(b.w);
      sa[i] = t;
    }
  };
  auto write_l = [&](int buf){
    #pragma unroll
    for (int i=0;i<4;i++){
      int r = i*32 + srow;
      int j = ((tid&7) ^ (r & 7)) * 8;
      *(bf16x8*)&lA[buf][r*64 + j] = sa[i];
    }
  };
  auto compute = [&](int buf, int kb){
    #pragma unroll
    for (int ksub=0; ksub<2; ksub++){
      const unsigned short* wb = W1f + (((chunk*16 + kb)*2 + ksub)*8 + nh*4)*512 + lane*8;
      bf16x8 af[4], bg[4];
      #pragma unroll
      for (int nt=0;nt<4;nt++) bg[nt] = *(const bf16x8*)(wb + nt*512);
      #pragma unroll
      for (int mt=0;mt<4;mt++){
        int r = mh*64 + mt*16 + (lane&15);
        int p = (ksub*4 + (lane>>4)) ^ (r&7);
        af[mt] = *(const bf16x8*)&lA[buf][r*64 + p*8];
      }
      #pragma unroll
      for (int mt=0;mt<4;mt++)
        #pragma unroll
        for (int nt=0;nt<4;nt++)
          acc[mt][nt] = __builtin_amdgcn_mfma_f32_16x16x32_bf16(af[mt], bg[nt], acc[mt][nt], 0,0,0);
    }
  };

  load_g(0);
  write_l(0);
  __syncthreads();
  for (int kb = 0; kb < 8; kb++){
    if (kb + 1 < 8) load_g(kb+1);
    compute(kb & 1, kb);
    if (kb + 1 < 8) write_l((kb+1) & 1);
    __syncthreads();
  }

  #pragma unroll
  for (int nt=0; nt<4; nt++){
    int col = chunk*128 + nh*64 + nt*16 + (lane & 15);
    #pragma unroll
    for (int mt=0; mt<4; mt++){
      #pragma unroll
      for (int r=0;r<4;r++){
        long row = m0 + mh*64 + mt*16 + (lane>>4)*4 + r;
        Ys[row*1024 + col] = acc[mt][nt][r];
      }
    }
  }
}

// ---------------- pass 1: GEMM1-z stats, X-resident (round-3 proven) ----------------
__global__ __launch_bounds__(256, 2) void gemm1_stats(
    const float* __restrict__ action,
    const unsigned short* __restrict__ XOA,
    const unsigned short* __restrict__ W1f,
    const float* __restrict__ Ys,
    float* __restrict__ bnsum, float* __restrict__ bnsq){
  __shared__ __align__(16) unsigned short stage[4][8192];  // kbp 4..7
  const int tid = threadIdx.x;
  const int lane = tid & 63;
  const int w = tid >> 6;
  const long m0 = (long)blockIdx.x * 64;
  const int rowg = w >> 1, colg = w & 1;    // 2x2 warp grid over 64x128 chunk

  // ---- stage X z-half once ----
  #pragma unroll
  for (int kbp = 4; kbp < 8; kbp++){
    #pragma unroll
    for (int i=0;i<4;i++){
      int ch = i*256 + tid;
      int row = ch >> 4, kc = ch & 15;
      long R = m0 + row;
      bf16x8 t;
      if (kbp == 6){
        const float* sp = action + R*128 + kc*8;
        float4 a = *(const float4*)sp;
        float4 b = *(const float4*)(sp + 4);
        t[0]=(short)f2bf(a.x); t[1]=(short)f2bf(a.y); t[2]=(short)f2bf(a.z); t[3]=(short)f2bf(a.w);
        t[4]=(short)f2bf(b.x); t[5]=(short)f2bf(b.y); t[6]=(short)f2bf(b.z); t[7]=(short)f2bf(b.w);
      } else {
        int col = (kbp < 6) ? ((kbp-4)*128) : 256;
        t = *(const bf16x8*)&XOA[R*384 + col + kc*8];
      }
      int j = (kc ^ (row & 7)) * 8;
      *(bf16x8*)&stage[kbp-4][row*128 + j] = t;
    }
  }
  __syncthreads();

  const long rbb = m0 >> 5;   // first state row of this block
  for (int chunk = 0; chunk < 8; chunk++){
    f32x4 acc[2][4];
    #pragma unroll
    for (int rt=0;rt<2;rt++){
      long rb = rbb + ((rowg*32 + rt*16) >> 5);
      #pragma unroll
      for (int ct=0;ct<4;ct++){
        int col = chunk*128 + colg*64 + ct*16 + (lane & 15);
        float v = Ys[rb*1024 + col];
        f32x4 z = {v,v,v,v}; acc[rt][ct] = z;
      }
    }
    #pragma unroll
    for (int kbp=4; kbp<8; kbp++){
      #pragma unroll
      for (int ks4=0; ks4<4; ks4++){
        const int kb = kbp*2 + (ks4 >> 1);
        const int ksub = ks4 & 1;
        const unsigned short* wb = W1f + (((chunk*16 + kb)*2 + ksub)*8 + colg*4)*512 + lane*8;
        bf16x8 af[2], bg[4];
        #pragma unroll
        for (int ct=0;ct<4;ct++) bg[ct] = *(const bf16x8*)(wb + ct*512);
        #pragma unroll
        for (int rt=0;rt<2;rt++){
          int r = rowg*32 + rt*16 + (lane&15);
          int p = (ks4*4 + (lane>>4)) ^ (r&7);
          af[rt] = *(const bf16x8*)&stage[kbp-4][r*128 + p*8];
        }
        #pragma unroll
        for (int rt=0;rt<2;rt++)
          #pragma unroll
          for (int ct=0;ct<4;ct++)
            acc[rt][ct] = __builtin_amdgcn_mfma_f32_16x16x32_bf16(af[rt], bg[ct], acc[rt][ct], 0,0,0);
      }
    }
    // stats epilogue for this chunk
    #pragma unroll
    for (int ct=0;ct<4;ct++){
      int col = chunk*128 + colg*64 + ct*16 + (lane & 15);
      float s = 0.f, q = 0.f;
      #pragma unroll
      for (int rt=0;rt<2;rt++)
        #pragma unroll
        for (int r=0;r<4;r++){
          float v = acc[rt][ct][r];
          s += v; q += v*v;
        }
      s += __shfl_down(s, 32); q += __shfl_down(q, 32);
      s += __shfl_down(s, 16); q += __shfl_down(q, 16);
      if (lane < 16){
        atomicAdd(&bnsum[col], s);
        atomicAdd(&bnsq[col], q);
      }
    }
  }
}

// ---------------- BN finalize ----------------
__global__ void bn_finalize(const float* __restrict__ sum, const float* __restrict__ sq,
                            const float* __restrict__ gamma, const float* __restrict__ beta,
                            float* __restrict__ a, float* __restrict__ c, int N){
  int i = blockIdx.x*256 + threadIdx.x;
  if (i >= N) return;
  const float invM = 1.0f / 131072.0f;
  float mu = sum[i]*invM;
  float var = sq[i]*invM - mu*mu;
  float s = rsqrtf(var + 1e-5f) * gamma[i];
  a[i] = s;
  c[i] = beta[i] - mu*s;
}

// ---------------- pass 2: fused GEMM1-z recompute -> BN1+ReLU -> GEMM2 (round-3 proven) ----------------
__global__ __launch_bounds__(256, 2) void gemm12(
    const float* __restrict__ action,
    const unsigned short* __restrict__ XOA,
    const unsigned short* __restrict__ W1f,
    const unsigned short* __restrict__ W2f,
    const float* __restrict__ Ys,
    const float* __restrict__ a1, const float* __restrict__ c1,
    unsigned short* __restrict__ Y2,
    float* __restrict__ bnsum, float* __restrict__ bnsq){
  __shared__ __align__(16) unsigned short stage[4][8192];  // X z-half, kbp 4..7
  __shared__ __align__(16) unsigned short h1c[8192];       // 64x128, XOR-swizzled
  const int tid = threadIdx.x;
  const int lane = tid & 63;
  const int w = tid >> 6;
  const long m0 = (long)blockIdx.x * 64;
  const int rowgA = w >> 1, colgA = w & 1;   // phase A: 2x2 over 64x128
  const int rgB = w >> 1, cgB = w & 1;       // phase B: 2x2 over 64x512

  // ---- stage X z-half once ----
  #pragma unroll
  for (int kbp = 4; kbp < 8; kbp++){
    #pragma unroll
    for (int i=0;i<4;i++){
      int ch = i*256 + tid;
      int row = ch >> 4, kc = ch & 15;
      long R = m0 + row;
      bf16x8 t;
      if (kbp == 6){
        const float* sp = action + R*128 + kc*8;
        float4 a = *(const float4*)sp;
        float4 b = *(const float4*)(sp + 4);
        t[0]=(short)f2bf(a.x); t[1]=(short)f2bf(a.y); t[2]=(short)f2bf(a.z); t[3]=(short)f2bf(a.w);
        t[4]=(short)f2bf(b.x); t[5]=(short)f2bf(b.y); t[6]=(short)f2bf(b.z); t[7]=(short)f2bf(b.w);
      } else {
        int col = (kbp < 6) ? ((kbp-4)*128) : 256;
        t = *(const bf16x8*)&XOA[R*384 + col + kc*8];
      }
      int j = (kc ^ (row & 7)) * 8;
      *(bf16x8*)&stage[kbp-4][row*128 + j] = t;
    }
  }

  f32x4 acc2[2][16];
  #pragma unroll
  for (int a=0;a<2;a++)
    #pragma unroll
    for (int b=0;b<16;b++){ f32x4 z = {0.f,0.f,0.f,0.f}; acc2[a][b] = z; }

  const long rbb = m0 >> 5;
  __syncthreads();   // stage ready

  for (int nt = 0; nt < 8; nt++){
    // ---- phase A: acc1 = Ys + X_z @ W1_z^T (chunk nt) ----
    f32x4 acc1[2][4];
    #pragma unroll
    for (int rt=0;rt<2;rt++){
      long rb = rbb + ((rowgA*32 + rt*16) >> 5);
      #pragma unroll
      for (int ct=0;ct<4;ct++){
        int col = nt*128 + colgA*64 + ct*16 + (lane & 15);
        float v = Ys[rb*1024 + col];
        f32x4 z = {v,v,v,v}; acc1[rt][ct] = z;
      }
    }
    #pragma unroll
    for (int kbp=4; kbp<8; kbp++){
      #pragma unroll
      for (int ks4=0; ks4<4; ks4++){
        const int kb = kbp*2 + (ks4 >> 1);
        const int ksub = ks4 & 1;
        const unsigned short* wb = W1f + (((nt*16 + kb)*2 + ksub)*8 + colgA*4)*512 + lane*8;
        bf16x8 af[2], bg[4];
        #pragma unroll
        for (int ct=0;ct<4;ct++) bg[ct] = *(const bf16x8*)(wb + ct*512);
        #pragma unroll
        for (int rt=0;rt<2;rt++){
          int r = rowgA*32 + rt*16 + (lane&15);
          int p = (ks4*4 + (lane>>4)) ^ (r&7);
          af[rt] = *(const bf16x8*)&stage[kbp-4][r*128 + p*8];
        }
        #pragma unroll
        for (int rt=0;rt<2;rt++)
          #pragma unroll
          for (int ct=0;ct<4;ct++)
            acc1[rt][ct] = __builtin_amdgcn_mfma_f32_16x16x32_bf16(af[rt], bg[ct], acc1[rt][ct], 0,0,0);
      }
    }

    __syncthreads();   // prev nt's phase-B h1c reads complete

    // ---- BN1 + relu -> h1c (XOR-swizzled) ----
    #pragma unroll
    for (int ct=0;ct<4;ct++){
      int lcol = colgA*64 + ct*16 + (lane&15);
      float av = a1[nt*128 + lcol];
      float cv = c1[nt*128 + lcol];
      #pragma unroll
      for (int rt=0;rt<2;rt++)
        #pragma unroll
        for (int r=0;r<4;r++){
          int row = rowgA*32 + rt*16 + (lane>>4)*4 + r;
          float h = fmaxf(fmaf(acc1[rt][ct][r], av, cv), 0.f);
          int sc = (lcol & 7) | ((((lcol >> 3) ^ (row & 7)) & 15) << 3);
          h1c[row*128 + sc] = f2bf(h);
        }
    }
    __syncthreads();   // h1c ready

    // ---- phase B: acc2 += h1c @ W2^T ----
    #pragma unroll
    for (int kh=0;kh<2;kh++){
      #pragma unroll
      for (int ksub=0;ksub<2;ksub++){
        bf16x8 af[2];
        #pragma unroll
        for (int rt=0;rt<2;rt++){
          int row = rgB*32 + rt*16 + (lane&15);
          int g0 = kh*8 + ksub*4 + (lane>>4);
          int gs = g0 ^ (row & 7);
          af[rt] = *(const bf16x8*)&h1c[row*128 + gs*8];
        }
        #pragma unroll
        for (int cth=0;cth<2;cth++){
          const unsigned short* wb = W2f + ((((nt*2 + kh)*2 + ksub)*32) + cgB*16 + cth*8)*512 + lane*8;
          bf16x8 bg[8];
          #pragma unroll
          for (int ct=0;ct<8;ct++) bg[ct] = *(const bf16x8*)(wb + ct*512);
          #pragma unroll
          for (int rt=0;rt<2;rt++)
            #pragma unroll
            for (int ct=0;ct<8;ct++)
              acc2[rt][cth*8+ct] = __builtin_amdgcn_mfma_f32_16x16x32_bf16(af[rt], bg[ct], acc2[rt][cth*8+ct], 0,0,0);
        }
      }
    }
    // no barrier here: next nt's first barrier orders h1c reads vs rewrite
  }

  // epilogue: Y2 bf16 store + BN2 stats
  #pragma unroll
  for (int ct=0;ct<16;ct++){
    int col = cgB*256 + ct*16 + (lane&15);
    float s = 0.f, q = 0.f;
    #pragma unroll
    for (int rt=0;rt<2;rt++)
      #pragma unroll
      for (int r=0;r<4;r++){
        long row = m0 + rgB*32 + rt*16 + (lane>>4)*4 + r;
        unsigned short ub = f2bf(acc2[rt][ct][r]);
        Y2[row*512 + col] = ub;
        float vq = bf2f(ub);
        s += vq; q += vq*vq;
      }
    s += __shfl_down(s, 32); q += __shfl_down(q, 32);
    s += __shfl_down(s, 16); q += __shfl_down(q, 16);
    if (lane < 16){
      atomicAdd(&bnsum[col], s);
      atomicAdd(&bnsq[col], q);
    }
  }
}

// ---------------- layer3 ----------------
__global__ __launch_bounds__(256) void final_kernel(
    const unsigned short* __restrict__ Y2,
    const float* __restrict__ a2, const float* __restrict__ c2,
    const float* __restrict__ W3, const float* __restrict__ b3, float* __restrict__ Q){
  const int tid = threadIdx.x;
  const int lane = tid & 63, wv = tid >> 6;
  const int wid = blockIdx.x*4 + wv;
  const int cb = lane*8;
  float4 a0 = *(const float4*)&a2[cb], a1 = *(const float4*)&a2[cb+4];
  float4 c0 = *(const float4*)&c2[cb], c1 = *(const float4*)&c2[cb+4];
  float4 w0 = *(const float4*)&W3[cb], w1 = *(const float4*)&W3[cb+4];
  const float b3v = b3[0];
  for (long row = wid; row < NROW; row += 4096){
    uint4 u = *(const uint4*)(Y2 + row*512 + cb);
    float y0 = bf2f(u.x & 0xffffu), y1 = bf2f(u.x >> 16);
    float y2 = bf2f(u.y & 0xffffu), y3 = bf2f(u.y >> 16);
    float y4 = bf2f(u.z & 0xffffu), y5 = bf2f(u.z >> 16);
    float y6 = bf2f(u.w & 0xffffu), y7 = bf2f(u.w >> 16);
    float t = fmaxf(fmaf(y0,a0.x,c0.x),0.f)*w0.x
            + fmaxf(fmaf(y1,a0.y,c0.y),0.f)*w0.y
            + fmaxf(fmaf(y2,a0.z,c0.z),0.f)*w0.z
            + fmaxf(fmaf(y3,a0.w,c0.w),0.f)*w0.w
            + fmaxf(fmaf(y4,a1.x,c1.x),0.f)*w1.x
            + fmaxf(fmaf(y5,a1.y,c1.y),0.f)*w1.y
            + fmaxf(fmaf(y6,a1.z,c1.z),0.f)*w1.z
            + fmaxf(fmaf(y7,a1.w,c1.w),0.f)*w1.w;
    #pragma unroll
    for (int off=32; off>=1; off>>=1) t += __shfl_down(t, off);
    if (lane == 0) Q[row] = t + b3v;
  }
}

// ---------------- launch ----------------
extern "C" void kernel_launch(void* const* d_in, const int* in_sizes, int n_in,
                              void* d_out, int out_size, void* d_ws, size_t ws_size,
                              hipStream_t stream){
  (void)in_sizes; (void)n_in; (void)out_size;
  if (ws_size < NEED2) return;   // proven to fit in round 2

  const float* state  = (const float*)d_in[0];
  const float* action = (const float*)d_in[1];
  const float* w_ih_f = (const float*)d_in[2];
  const float* w_hh_f = (const float*)d_in[3];
  const float* b_ih_f = (const float*)d_in[4];
  const float* b_hh_f = (const float*)d_in[5];
  const float* w_ih_r = (const float*)d_in[6];
  const float* w_hh_r = (const float*)d_in[7];
  const float* b_ih_r = (const float*)d_in[8];
  const float* b_hh_r = (const float*)d_in[9];
  const float* W1  = (const float*)d_in[10];
  const float* b1  = (const float*)d_in[11];
  const float* g1  = (const float*)d_in[12];
  const float* be1 = (const float*)d_in[13];
  const float* W2  = (const float*)d_in[14];
  const float* b2  = (const float*)d_in[15];
  const float* g2  = (const float*)d_in[16];
  const float* be2 = (const float*)d_in[17];
  const float* W3  = (const float*)d_in[18];
  const float* b3  = (const float*)d_in[19];
  (void)b1; (void)b2;  // cancel inside BatchNorm

  char* ws = (char*)d_ws;
  unsigned short* XOA = (unsigned short*)(ws + WS_XOA);
  unsigned short* Y2  = (unsigned short*)(ws + WS_Y2);
  float* Ysp = (float*)(ws + WS_YS);
  char* sm = ws + WS_SM;
  unsigned short* W1f = (unsigned short*)(sm + SM_W1F);
  unsigned short* W2f = (unsigned short*)(sm + SM_W2F);
  unsigned short* wih = (unsigned short*)(sm + SM_WIH);
  unsigned short* whh = (unsigned short*)(sm + SM_WHH);
  float* bias   = (float*)(sm + SM_BIAS);
  float* bnsum1 = (float*)(sm + SM_STAT);
  float* bnsq1  = (float*)(sm + SM_STAT + 0x1000);
  float* bnsum2 = (float*)(sm + SM_STAT + 0x2000);
  float* bnsq2  = (float*)(sm + SM_STAT + 0x2800);
  float* a1 = (float*)(sm + SM_A1);
  float* c1 = (float*)(sm + SM_C1);
  float* a2 = (float*)(sm + SM_A2);
  float* c2 = (float*)(sm + SM_C2);
  float* qout = (float*)d_out;
  float* regout = qout + 131072;

  hipMemsetAsync(bnsum1, 0, 0x3000, stream);
  hipMemsetAsync(regout, 0, 4, stream);

  prep_kernel<<<1024, 256, 0, stream>>>(w_ih_f, w_hh_f, b_ih_f, b_hh_f,
                                        w_ih_r, w_hh_r, b_ih_r, b_hh_r,
                                        W1, W2, W1f, W2f, wih, whh, bias);
  reg_kernel<<<256, 256, 0, stream>>>(w_ih_f, w_hh_f, b_ih_f, b_hh_f,
                                      w_ih_r, w_hh_r, b_ih_r, b_hh_r,
                                      W1, b1, g1, be1, W2, b2, g2, be2, W3, b3, regout);
  ys_kernel<<<dim3(32, 8), 256, 0, stream>>>(state, W1f, Ysp);
  lstm_kernel<<<dim3(256,2), 256, 0, stream>>>(action, wih, whh, bias, XOA);
  attn_pack<<<4096, 256, 0, stream>>>(action, XOA);
  gemm1_stats<<<2048, 256, 0, stream>>>(action, XOA, W1f, Ysp, bnsum1, bnsq1);
  bn_finalize<<<4, 256, 0, stream>>>(bnsum1, bnsq1, g1, be1, a1, c1, 1024);
  gemm12<<<2048, 256, 0, stream>>>(action, XOA, W1f, W2f, Ysp, a1, c1, Y2, bnsum2, bnsq2);
  bn_finalize<<<2, 256, 0, stream>>>(bnsum2, bnsq2, g2, be2, a2, c2, 512);
  final_kernel<<<1024, 256, 0, stream>>>(Y2, a2, c2, W3, b3, qout);
}

// Round 6
// 1203.269 us; speedup vs baseline: 1.2569x; 1.2440x over previous
//
#include <hip/hip_runtime.h>
#include <cstdint>

// ---------------- common ----------------
#define NROW 131072   // B*K

typedef short bf16x8 __attribute__((ext_vector_type(8)));
typedef float f32x4 __attribute__((ext_vector_type(4)));

__device__ __forceinline__ unsigned short f2bf(float f){
  unsigned u = __builtin_bit_cast(unsigned, f);
  u += 0x7fffu + ((u >> 16) & 1u);
  return (unsigned short)(u >> 16);
}
__device__ __forceinline__ float bf2f(unsigned v){
  unsigned u = v << 16; return __builtin_bit_cast(float, u);
}
__device__ __forceinline__ float sigf(float x){ return 1.0f/(1.0f + __expf(-x)); }
__device__ __forceinline__ float tanh_fast(float x){ return 2.0f/(1.0f + __expf(-2.0f*x)) - 1.0f; }

// ---------- workspace layout (byte offsets) ----------
// XOA  [0x00000000, 0x06000000)  131072 x 384 bf16 [Of|Or|A]  (96 MiB)
// Y2   [0x06000000, 0x0E000000)  131072 x 512 bf16            (128 MiB)
// SM   [0x0E000000, 0x0E390000)  small region
// Ys   [0x0E390000, 0x0F390000)  4096 x 1024 fp32 (16 MiB)
#define WS_XOA  0x00000000UL
#define WS_Y2   0x06000000UL
#define WS_SM   0x0E000000UL
#define WS_YS   0x0E390000UL
#define NEED2   0x0F390000UL   // proven to fit in round 2
// small-region offsets (relative to WS_SM)
#define SM_W1F  0x000000       // W1 frag layout, 2 MiB
#define SM_W2F  0x200000       // W2 frag layout, 1 MiB
#define SM_WIH  0x300000
#define SM_WHH  0x340000
#define SM_BIAS 0x380000
#define SM_STAT 0x381000
#define SM_A1   0x384000
#define SM_C1   0x385000
#define SM_A2   0x386000
#define SM_C2   0x386800

// ---------------- prep: frag-layout weight conversion ----------------
// lstm frag (N=512,K=128): element j of slot ((nt*4+kt)*64+lane)
//   = W[nt*16+(lane&15)][kt*32+(lane>>4)*8+j]
__device__ __forceinline__ void conv_frag(const float* __restrict__ src, unsigned short* __restrict__ dst,
                                          long g, long T){
  for (long i = g; i < 8192; i += T){
    int lane = (int)(i & 63);
    int blk  = (int)(i >> 6);
    int nt = blk >> 2, kt = blk & 3;
    const float* sp = src + (nt*16 + (lane&15))*128 + kt*32 + (lane>>4)*8;
    float4 a = *(const float4*)sp;
    float4 b = *(const float4*)(sp+4);
    uint4 o;
    o.x = (unsigned)f2bf(a.x) | ((unsigned)f2bf(a.y) << 16);
    o.y = (unsigned)f2bf(a.z) | ((unsigned)f2bf(a.w) << 16);
    o.z = (unsigned)f2bf(b.x) | ((unsigned)f2bf(b.y) << 16);
    o.w = (unsigned)f2bf(b.z) | ((unsigned)f2bf(b.w) << 16);
    *((uint4*)dst + i) = o;
  }
}

// W1f: slot = (((chunk*16 + kb)*2 + ksub)*8 + c16)*64 + lane ; elem j =
//   W1[chunk*128 + c16*16 + (lane&15)][kb*64 + ksub*32 + (lane>>4)*8 + j]
// W2f: slot = (((nt*2 + kh)*2 + ksub)*32 + c16)*64 + lane ; elem j =
//   W2[c16*16 + (lane&15)][nt*128 + kh*64 + ksub*32 + (lane>>4)*8 + j]
__global__ __launch_bounds__(256) void prep_kernel(
    const float* __restrict__ wihf, const float* __restrict__ whhf,
    const float* __restrict__ bihf, const float* __restrict__ bhhf,
    const float* __restrict__ wihr, const float* __restrict__ whhr,
    const float* __restrict__ bihr, const float* __restrict__ bhhr,
    const float* __restrict__ W1, const float* __restrict__ W2,
    unsigned short* __restrict__ W1f, unsigned short* __restrict__ W2f,
    unsigned short* __restrict__ wih, unsigned short* __restrict__ whh,
    float* __restrict__ bias){
  const long T = (long)gridDim.x * 256;
  const long g = (long)blockIdx.x * 256 + threadIdx.x;
  for (long s = g; s < 131072; s += T){
    int lane = (int)(s & 63);
    long t = s >> 6;
    int c16 = (int)(t & 7);
    long t2 = t >> 3;
    int ksub = (int)(t2 & 1);
    long t3 = t2 >> 1;
    int kb = (int)(t3 & 15);
    int chunk = (int)(t3 >> 4);
    const float* sp = W1 + (long)(chunk*128 + c16*16 + (lane&15))*1024 + kb*64 + ksub*32 + (lane>>4)*8;
    float4 a = *(const float4*)sp;
    float4 b = *(const float4*)(sp+4);
    uint4 o;
    o.x = (unsigned)f2bf(a.x) | ((unsigned)f2bf(a.y) << 16);
    o.y = (unsigned)f2bf(a.z) | ((unsigned)f2bf(a.w) << 16);
    o.z = (unsigned)f2bf(b.x) | ((unsigned)f2bf(b.y) << 16);
    o.w = (unsigned)f2bf(b.z) | ((unsigned)f2bf(b.w) << 16);
    *((uint4*)W1f + s) = o;
  }
  for (long s = g; s < 65536; s += T){
    int lane = (int)(s & 63);
    long t = s >> 6;
    int c16 = (int)(t & 31);
    long t2 = t >> 5;
    int ksub = (int)(t2 & 1);
    long t3 = t2 >> 1;
    int kh = (int)(t3 & 1);
    int nt = (int)(t3 >> 1);
    const float* sp = W2 + (long)(c16*16 + (lane&15))*1024 + nt*128 + kh*64 + ksub*32 + (lane>>4)*8;
    float4 a = *(const float4*)sp;
    float4 b = *(const float4*)(sp+4);
    uint4 o;
    o.x = (unsigned)f2bf(a.x) | ((unsigned)f2bf(a.y) << 16);
    o.y = (unsigned)f2bf(a.z) | ((unsigned)f2bf(a.w) << 16);
    o.z = (unsigned)f2bf(b.x) | ((unsigned)f2bf(b.y) << 16);
    o.w = (unsigned)f2bf(b.z) | ((unsigned)f2bf(b.w) << 16);
    *((uint4*)W2f + s) = o;
  }
  conv_frag(wihf, wih, g, T);
  conv_frag(whhf, whh, g, T);
  conv_frag(wihr, wih + 65536, g, T);
  conv_frag(whhr, whh + 65536, g, T);
  for (long i = g; i < 512; i += T){
    bias[i]       = bihf[i] + bhhf[i];
    bias[512 + i] = bihr[i] + bhhr[i];
  }
}

// ---------------- reg = sum mean(p^2) ----------------
__global__ __launch_bounds__(256) void reg_kernel(
    const float* p0, const float* p1, const float* p2, const float* p3,
    const float* p4, const float* p5, const float* p6, const float* p7,
    const float* p8, const float* p9, const float* p10, const float* p11,
    const float* p12, const float* p13, const float* p14, const float* p15,
    const float* p16, const float* p17, float* __restrict__ out){
  const int tid = threadIdx.x;
  const long T = (long)gridDim.x * 256;
  const long g = (long)blockIdx.x * 256 + tid;
  float local = 0.f;
#define RLOOP(P, SZ) for (long i = g; i < (SZ); i += T){ float v = (P)[i]; local += v*v*(1.0f/(float)(SZ)); }
  RLOOP(p0, 65536) RLOOP(p1, 65536) RLOOP(p2, 512) RLOOP(p3, 512)
  RLOOP(p4, 65536) RLOOP(p5, 65536) RLOOP(p6, 512) RLOOP(p7, 512)
  RLOOP(p8, 1048576) RLOOP(p9, 1024) RLOOP(p10, 1024) RLOOP(p11, 1024)
  RLOOP(p12, 524288) RLOOP(p13, 512) RLOOP(p14, 512) RLOOP(p15, 512)
  RLOOP(p16, 512) RLOOP(p17, 1)
#undef RLOOP
  #pragma unroll
  for (int off=32; off>=1; off>>=1) local += __shfl_down(local, off);
  __shared__ float wsum[4];
  if ((tid & 63) == 0) wsum[tid>>6] = local;
  __syncthreads();
  if (tid == 0) atomicAdd(out, wsum[0]+wsum[1]+wsum[2]+wsum[3]);
}

// ---------------- BiLSTM: 32 rows/block; wih in VGPRs, whh in LDS ----------------
// Weight streams eliminated: wih slice (32 frags = 128 VGPR) loaded once into
// registers; whh (128 KB) staged once into LDS. Per-step traffic = action 8 KB
// + LDS reads only. Same MFMA operand values + order -> bitwise identical h.
__global__ __launch_bounds__(256, 1) void lstm_kernel(
    const float* __restrict__ action,
    const unsigned short* __restrict__ wih_all,
    const unsigned short* __restrict__ whh_all,
    const float* __restrict__ bias_all,
    unsigned short* __restrict__ XOA){
  const int dir = blockIdx.y;
  const int b0 = blockIdx.x * 32;
  const unsigned short* __restrict__ wih = wih_all + dir * 65536;
  const unsigned short* __restrict__ whh = whh_all + dir * 65536;
  const float* __restrict__ bias = bias_all + dir * 512;
  __shared__ __align__(16) unsigned short whl[65536];   // whh, 128 KB
  __shared__ __align__(16) unsigned short lh[32*136];
  const int tid = threadIdx.x;
  const int lane = tid & 63;
  const int wv = tid >> 6;
  const int l15 = lane & 15, l4 = lane >> 4;
  // stage whh -> LDS
  for (int i = tid; i < 8192; i += 256)
    *((uint4*)whl + i) = *((const uint4*)whh + i);
  for (int i = tid; i < 32*136; i += 256) lh[i] = 0;
  // wih wave-slice -> registers (static indices only)
  bf16x8 wr[4][2][4];   // [G2][qq][kt]
  #pragma unroll
  for (int G2=0;G2<4;G2++)
    #pragma unroll
    for (int qq=0;qq<2;qq++){
      const int nt = G2*8 + 2*wv + qq;
      #pragma unroll
      for (int kt=0;kt<4;kt++)
        wr[G2][qq][kt] = *(const bf16x8*)&wih[((nt*4 + kt)*64 + lane)*8];
    }
  float bias_r[2][4];
  #pragma unroll
  for (int qq=0;qq<2;qq++)
    #pragma unroll
    for (int G2=0;G2<4;G2++)
      bias_r[qq][G2] = bias[G2*128 + (2*wv+qq)*16 + l15];
  f32x4 cst[2][2];
  #pragma unroll
  for (int mt=0;mt<2;mt++)
    #pragma unroll
    for (int qq=0;qq<2;qq++){ f32x4 z = {0.f,0.f,0.f,0.f}; cst[mt][qq] = z; }
  __syncthreads();

  for (int s = 0; s < 32; s++){
    const int korig = dir ? (31 - s) : s;
    bf16x8 ha[2][4];
    #pragma unroll
    for (int mt=0;mt<2;mt++)
      #pragma unroll
      for (int kt=0;kt<4;kt++)
        ha[mt][kt] = *(const bf16x8*)&lh[(mt*16 + l15)*136 + kt*32 + l4*8];
    __syncthreads();
    bf16x8 xa[2][4];
    #pragma unroll
    for (int mt=0;mt<2;mt++)
      #pragma unroll
      for (int kt=0;kt<4;kt++){
        const float* sp = action + ((long)(b0 + mt*16 + l15)*32 + korig)*128 + kt*32 + l4*8;
        float4 a = *(const float4*)sp;
        float4 b = *(const float4*)(sp + 4);
        bf16x8 t;
        t[0]=(short)f2bf(a.x); t[1]=(short)f2bf(a.y); t[2]=(short)f2bf(a.z); t[3]=(short)f2bf(a.w);
        t[4]=(short)f2bf(b.x); t[5]=(short)f2bf(b.y); t[6]=(short)f2bf(b.z); t[7]=(short)f2bf(b.w);
        xa[mt][kt] = t;
      }
    f32x4 acc[2][2][4];
    #pragma unroll
    for (int mt=0;mt<2;mt++)
      #pragma unroll
      for (int qq=0;qq<2;qq++)
        #pragma unroll
        for (int G2=0;G2<4;G2++){
          float bb = bias_r[qq][G2];
          f32x4 z = {bb,bb,bb,bb};
          acc[mt][qq][G2] = z;
        }
    #pragma unroll
    for (int G2=0;G2<4;G2++)
      #pragma unroll
      for (int qq=0;qq<2;qq++){
        const int nt = G2*8 + 2*wv + qq;
        #pragma unroll
        for (int kt=0;kt<4;kt++){
          acc[0][qq][G2] = __builtin_amdgcn_mfma_f32_16x16x32_bf16(xa[0][kt], wr[G2][qq][kt], acc[0][qq][G2], 0,0,0);
          acc[1][qq][G2] = __builtin_amdgcn_mfma_f32_16x16x32_bf16(xa[1][kt], wr[G2][qq][kt], acc[1][qq][G2], 0,0,0);
        }
        #pragma unroll
        for (int kt=0;kt<4;kt++){
          bf16x8 bw = *(const bf16x8*)&whl[((nt*4 + kt)*64 + lane)*8];
          acc[0][qq][G2] = __builtin_amdgcn_mfma_f32_16x16x32_bf16(ha[0][kt], bw, acc[0][qq][G2], 0,0,0);
          acc[1][qq][G2] = __builtin_amdgcn_mfma_f32_16x16x32_bf16(ha[1][kt], bw, acc[1][qq][G2], 0,0,0);
        }
      }
    #pragma unroll
    for (int mt=0;mt<2;mt++)
      #pragma unroll
      for (int qq=0;qq<2;qq++){
        const int hcol = (2*wv+qq)*16 + l15;
        #pragma unroll
        for (int r=0;r<4;r++){
          float iv = acc[mt][qq][0][r];
          float fv = acc[mt][qq][1][r];
          float gv = acc[mt][qq][2][r];
          float ov = acc[mt][qq][3][r];
          float c = cst[mt][qq][r];
          c = sigf(fv)*c + sigf(iv)*tanh_fast(gv);
          float h = sigf(ov)*tanh_fast(c);
          cst[mt][qq][r] = c;
          const int row = mt*16 + l4*4 + r;
          unsigned short hb = f2bf(h);
          lh[row*136 + hcol] = hb;
          XOA[((long)(b0+row)*32 + korig)*384 + dir*128 + hcol] = hb;
        }
      }
    __syncthreads();
  }
}

// ---------------- attention (unchanged) ----------------
__global__ __launch_bounds__(256) void attn_pack(
    const float* __restrict__ action,
    unsigned short* __restrict__ XOA){
  const int b = blockIdx.x;
  const int tid = threadIdx.x;
  __shared__ __align__(16) float V[32][132];
  __shared__ __align__(16) float attw[32][33];
  const float* __restrict__ src = action + (long)b*32*128;
  for (int i = tid; i < 1024; i += 256){
    int r = i >> 5, c4 = i & 31;
    *(float4*)&V[r][c4*4] = *(const float4*)&src[r*128 + c4*4];
  }
  __syncthreads();
  const int i = tid >> 3, j0 = tid & 7;
  float sacc[4] = {0.f,0.f,0.f,0.f};
  for (int c=0;c<32;c++){
    float4 vi = *(const float4*)&V[i][c*4];
    #pragma unroll
    for (int jj=0;jj<4;jj++){
      float4 vj = *(const float4*)&V[j0 + jj*8][c*4];
      sacc[jj] += vi.x*vj.x + vi.y*vj.y + vi.z*vj.z + vi.w*vj.w;
    }
  }
  float m = fmaxf(fmaxf(sacc[0],sacc[1]), fmaxf(sacc[2],sacc[3]));
  #pragma unroll
  for (int off=1; off<8; off<<=1) m = fmaxf(m, __shfl_xor(m, off));
  float e0 = __expf(sacc[0]-m), e1 = __expf(sacc[1]-m), e2 = __expf(sacc[2]-m), e3 = __expf(sacc[3]-m);
  float ssum = e0+e1+e2+e3;
  #pragma unroll
  for (int off=1; off<8; off<<=1) ssum += __shfl_xor(ssum, off);
  float inv = 1.0f / ssum;
  attw[i][j0] = e0*inv; attw[i][j0+8] = e1*inv; attw[i][j0+16] = e2*inv; attw[i][j0+24] = e3*inv;
  __syncthreads();
  const int d0 = (tid & 7) * 16;
  float a[16];
  #pragma unroll
  for (int t=0;t<16;t++) a[t]=0.f;
  for (int j=0;j<32;j++){
    float w = attw[i][j];
    #pragma unroll
    for (int dd=0;dd<4;dd++){
      float4 v = *(const float4*)&V[j][d0 + dd*4];
      a[dd*4+0] += w*v.x; a[dd*4+1] += w*v.y; a[dd*4+2] += w*v.z; a[dd*4+3] += w*v.w;
    }
  }
  unsigned short* rowp = XOA + ((long)b*32 + i)*384;
  #pragma unroll
  for (int t=0;t<8;t++){
    ushort2 u; u.x = f2bf(a[t*2]); u.y = f2bf(a[t*2+1]);
    *(ushort2*)(rowp + 256 + d0 + t*2) = u;
  }
}

// ---------------- Ys = state @ W1[:, 0:512]^T  (state-broadcast trick) ----------------
// 4096 x 1024 fp32. K = 512 (kb 0..7). MFMA accumulation order identical to the
// unsplit chain → downstream results bitwise identical.
__global__ __launch_bounds__(256, 3) void ys_kernel(
    const float* __restrict__ state,
    const unsigned short* __restrict__ W1f,
    float* __restrict__ Ys){
  __shared__ __align__(16) unsigned short lA[2][8192];
  const int tid = threadIdx.x;
  const int lane = tid & 63;
  const long m0 = (long)blockIdx.x * 128;   // state row
  const int chunk = blockIdx.y;             // n-chunk of 128
  const int mh = (tid >> 6) >> 1, nh = (tid >> 6) & 1;
  f32x4 acc[4][4];
  #pragma unroll
  for (int a=0;a<4;a++)
    #pragma unroll
    for (int b=0;b<4;b++){ f32x4 z = {0.f,0.f,0.f,0.f}; acc[a][b] = z; }

  bf16x8 sa[4];
  const int srow = tid >> 3;
  const int sg   = (tid & 7) * 8;

  auto load_g = [&](int kb){
    const int k0 = kb << 6;
    #pragma unroll
    for (int i=0;i<4;i++){
      long r = m0 + i*32 + srow;
      const float* sp = state + r*512 + k0 + sg;
      float4 a = *(const float4*)sp;
      float4 b = *(const float4*)(sp + 4);
      bf16x8 t;
      t[0]=(short)f2bf(a.x); t[1]=(short)f2bf(a.y); t[2]=(short)f2bf(a.z); t[3]=(short)f2bf(a.w);
      t[4]=(short)f2bf(b.x); t[5]=(short)f2bf(b.y); t[6]=(short)f2bf(b.z); t[7]=(short)f2bf(b.w);
      sa[i] = t;
    }
  };
  auto write_l = [&](int buf){
    #pragma unroll
    for (int i=0;i<4;i++){
      int r = i*32 + srow;
      int j = ((tid&7) ^ (r & 7)) * 8;
      *(bf16x8*)&lA[buf][r*64 + j] = sa[i];
    }
  };
  auto compute = [&](int buf, int kb){
    #pragma unroll
    for (int ksub=0; ksub<2; ksub++){
      const unsigned short* wb = W1f + (((chunk*16 + kb)*2 + ksub)*8 + nh*4)*512 + lane*8;
      bf16x8 af[4], bg[4];
      #pragma unroll
      for (int nt=0;nt<4;nt++) bg[nt] = *(const bf16x8*)(wb + nt*512);
      #pragma unroll
      for (int mt=0;mt<4;mt++){
        int r = mh*64 + mt*16 + (lane&15);
        int p = (ksub*4 + (lane>>4)) ^ (r&7);
        af[mt] = *(const bf16x8*)&lA[buf][r*64 + p*8];
      }
      #pragma unroll
      for (int mt=0;mt<4;mt++)
        #pragma unroll
        for (int nt=0;nt<4;nt++)
          acc[mt][nt] = __builtin_amdgcn_mfma_f32_16x16x32_bf16(af[mt], bg[nt], acc[mt][nt], 0,0,0);
    }
  };

  load_g(0);
  write_l(0);
  __syncthreads();
  for (int kb = 0; kb < 8; kb++){
    if (kb + 1 < 8) load_g(kb+1);
    compute(kb & 1, kb);
    if (kb + 1 < 8) write_l((kb+1) & 1);
    __syncthreads();
  }

  #pragma unroll
  for (int nt=0; nt<4; nt++){
    int col = chunk*128 + nh*64 + nt*16 + (lane & 15);
    #pragma unroll
    for (int mt=0; mt<4; mt++){
      #pragma unroll
      for (int r=0;r<4;r++){
        long row = m0 + mh*64 + mt*16 + (lane>>4)*4 + r;
        Ys[row*1024 + col] = acc[mt][nt][r];
      }
    }
  }
}

// ---------------- pass 1: GEMM1-z stats, X-resident (round-3 proven) ----------------
__global__ __launch_bounds__(256, 2) void gemm1_stats(
    const float* __restrict__ action,
    const unsigned short* __restrict__ XOA,
    const unsigned short* __restrict__ W1f,
    const float* __restrict__ Ys,
    float* __restrict__ bnsum, float* __restrict__ bnsq){
  __shared__ __align__(16) unsigned short stage[4][8192];  // kbp 4..7
  const int tid = threadIdx.x;
  const int lane = tid & 63;
  const int w = tid >> 6;
  const long m0 = (long)blockIdx.x * 64;
  const int rowg = w >> 1, colg = w & 1;    // 2x2 warp grid over 64x128 chunk

  // ---- stage X z-half once ----
  #pragma unroll
  for (int kbp = 4; kbp < 8; kbp++){
    #pragma unroll
    for (int i=0;i<4;i++){
      int ch = i*256 + tid;
      int row = ch >> 4, kc = ch & 15;
      long R = m0 + row;
      bf16x8 t;
      if (kbp == 6){
        const float* sp = action + R*128 + kc*8;
        float4 a = *(const float4*)sp;
        float4 b = *(const float4*)(sp + 4);
        t[0]=(short)f2bf(a.x); t[1]=(short)f2bf(a.y); t[2]=(short)f2bf(a.z); t[3]=(short)f2bf(a.w);
        t[4]=(short)f2bf(b.x); t[5]=(short)f2bf(b.y); t[6]=(short)f2bf(b.z); t[7]=(short)f2bf(b.w);
      } else {
        int col = (kbp < 6) ? ((kbp-4)*128) : 256;
        t = *(const bf16x8*)&XOA[R*384 + col + kc*8];
      }
      int j = (kc ^ (row & 7)) * 8;
      *(bf16x8*)&stage[kbp-4][row*128 + j] = t;
    }
  }
  __syncthreads();

  const long rbb = m0 >> 5;   // first state row of this block
  for (int chunk = 0; chunk < 8; chunk++){
    f32x4 acc[2][4];
    #pragma unroll
    for (int rt=0;rt<2;rt++){
      long rb = rbb + ((rowg*32 + rt*16) >> 5);
      #pragma unroll
      for (int ct=0;ct<4;ct++){
        int col = chunk*128 + colg*64 + ct*16 + (lane & 15);
        float v = Ys[rb*1024 + col];
        f32x4 z = {v,v,v,v}; acc[rt][ct] = z;
      }
    }
    #pragma unroll
    for (int kbp=4; kbp<8; kbp++){
      #pragma unroll
      for (int ks4=0; ks4<4; ks4++){
        const int kb = kbp*2 + (ks4 >> 1);
        const int ksub = ks4 & 1;
        const unsigned short* wb = W1f + (((chunk*16 + kb)*2 + ksub)*8 + colg*4)*512 + lane*8;
        bf16x8 af[2], bg[4];
        #pragma unroll
        for (int ct=0;ct<4;ct++) bg[ct] = *(const bf16x8*)(wb + ct*512);
        #pragma unroll
        for (int rt=0;rt<2;rt++){
          int r = rowg*32 + rt*16 + (lane&15);
          int p = (ks4*4 + (lane>>4)) ^ (r&7);
          af[rt] = *(const bf16x8*)&stage[kbp-4][r*128 + p*8];
        }
        #pragma unroll
        for (int rt=0;rt<2;rt++)
          #pragma unroll
          for (int ct=0;ct<4;ct++)
            acc[rt][ct] = __builtin_amdgcn_mfma_f32_16x16x32_bf16(af[rt], bg[ct], acc[rt][ct], 0,0,0);
      }
    }
    // stats epilogue for this chunk
    #pragma unroll
    for (int ct=0;ct<4;ct++){
      int col = chunk*128 + colg*64 + ct*16 + (lane & 15);
      float s = 0.f, q = 0.f;
      #pragma unroll
      for (int rt=0;rt<2;rt++)
        #pragma unroll
        for (int r=0;r<4;r++){
          float v = acc[rt][ct][r];
          s += v; q += v*v;
        }
      s += __shfl_down(s, 32); q += __shfl_down(q, 32);
      s += __shfl_down(s, 16); q += __shfl_down(q, 16);
      if (lane < 16){
        atomicAdd(&bnsum[col], s);
        atomicAdd(&bnsq[col], q);
      }
    }
  }
}

// ---------------- BN finalize ----------------
__global__ void bn_finalize(const float* __restrict__ sum, const float* __restrict__ sq,
                            const float* __restrict__ gamma, const float* __restrict__ beta,
                            float* __restrict__ a, float* __restrict__ c, int N){
  int i = blockIdx.x*256 + threadIdx.x;
  if (i >= N) return;
  const float invM = 1.0f / 131072.0f;
  float mu = sum[i]*invM;
  float var = sq[i]*invM - mu*mu;
  float s = rsqrtf(var + 1e-5f) * gamma[i];
  a[i] = s;
  c[i] = beta[i] - mu*s;
}

// ---------------- pass 2: fused GEMM1-z recompute -> BN1+ReLU -> GEMM2 (round-3 proven) ----------------
__global__ __launch_bounds__(256, 2) void gemm12(
    const float* __restrict__ action,
    const unsigned short* __restrict__ XOA,
    const unsigned short* __restrict__ W1f,
    const unsigned short* __restrict__ W2f,
    const float* __restrict__ Ys,
    const float* __restrict__ a1, const float* __restrict__ c1,
    unsigned short* __restrict__ Y2,
    float* __restrict__ bnsum, float* __restrict__ bnsq){
  __shared__ __align__(16) unsigned short stage[4][8192];  // X z-half, kbp 4..7
  __shared__ __align__(16) unsigned short h1c[8192];       // 64x128, XOR-swizzled
  const int tid = threadIdx.x;
  const int lane = tid & 63;
  const int w = tid >> 6;
  const long m0 = (long)blockIdx.x * 64;
  const int rowgA = w >> 1, colgA = w & 1;   // phase A: 2x2 over 64x128
  const int rgB = w >> 1, cgB = w & 1;       // phase B: 2x2 over 64x512

  // ---- stage X z-half once ----
  #pragma unroll
  for (int kbp = 4; kbp < 8; kbp++){
    #pragma unroll
    for (int i=0;i<4;i++){
      int ch = i*256 + tid;
      int row = ch >> 4, kc = ch & 15;
      long R = m0 + row;
      bf16x8 t;
      if (kbp == 6){
        const float* sp = action + R*128 + kc*8;
        float4 a = *(const float4*)sp;
        float4 b = *(const float4*)(sp + 4);
        t[0]=(short)f2bf(a.x); t[1]=(short)f2bf(a.y); t[2]=(short)f2bf(a.z); t[3]=(short)f2bf(a.w);
        t[4]=(short)f2bf(b.x); t[5]=(short)f2bf(b.y); t[6]=(short)f2bf(b.z); t[7]=(short)f2bf(b.w);
      } else {
        int col = (kbp < 6) ? ((kbp-4)*128) : 256;
        t = *(const bf16x8*)&XOA[R*384 + col + kc*8];
      }
      int j = (kc ^ (row & 7)) * 8;
      *(bf16x8*)&stage[kbp-4][row*128 + j] = t;
    }
  }

  f32x4 acc2[2][16];
  #pragma unroll
  for (int a=0;a<2;a++)
    #pragma unroll
    for (int b=0;b<16;b++){ f32x4 z = {0.f,0.f,0.f,0.f}; acc2[a][b] = z; }

  const long rbb = m0 >> 5;
  __syncthreads();   // stage ready

  for (int nt = 0; nt < 8; nt++){
    // ---- phase A: acc1 = Ys + X_z @ W1_z^T (chunk nt) ----
    f32x4 acc1[2][4];
    #pragma unroll
    for (int rt=0;rt<2;rt++){
      long rb = rbb + ((rowgA*32 + rt*16) >> 5);
      #pragma unroll
      for (int ct=0;ct<4;ct++){
        int col = nt*128 + colgA*64 + ct*16 + (lane & 15);
        float v = Ys[rb*1024 + col];
        f32x4 z = {v,v,v,v}; acc1[rt][ct] = z;
      }
    }
    #pragma unroll
    for (int kbp=4; kbp<8; kbp++){
      #pragma unroll
      for (int ks4=0; ks4<4; ks4++){
        const int kb = kbp*2 + (ks4 >> 1);
        const int ksub = ks4 & 1;
        const unsigned short* wb = W1f + (((nt*16 + kb)*2 + ksub)*8 + colgA*4)*512 + lane*8;
        bf16x8 af[2], bg[4];
        #pragma unroll
        for (int ct=0;ct<4;ct++) bg[ct] = *(const bf16x8*)(wb + ct*512);
        #pragma unroll
        for (int rt=0;rt<2;rt++){
          int r = rowgA*32 + rt*16 + (lane&15);
          int p = (ks4*4 + (lane>>4)) ^ (r&7);
          af[rt] = *(const bf16x8*)&stage[kbp-4][r*128 + p*8];
        }
        #pragma unroll
        for (int rt=0;rt<2;rt++)
          #pragma unroll
          for (int ct=0;ct<4;ct++)
            acc1[rt][ct] = __builtin_amdgcn_mfma_f32_16x16x32_bf16(af[rt], bg[ct], acc1[rt][ct], 0,0,0);
      }
    }

    __syncthreads();   // prev nt's phase-B h1c reads complete

    // ---- BN1 + relu -> h1c (XOR-swizzled) ----
    #pragma unroll
    for (int ct=0;ct<4;ct++){
      int lcol = colgA*64 + ct*16 + (lane&15);
      float av = a1[nt*128 + lcol];
      float cv = c1[nt*128 + lcol];
      #pragma unroll
      for (int rt=0;rt<2;rt++)
        #pragma unroll
        for (int r=0;r<4;r++){
          int row = rowgA*32 + rt*16 + (lane>>4)*4 + r;
          float h = fmaxf(fmaf(acc1[rt][ct][r], av, cv), 0.f);
          int sc = (lcol & 7) | ((((lcol >> 3) ^ (row & 7)) & 15) << 3);
          h1c[row*128 + sc] = f2bf(h);
        }
    }
    __syncthreads();   // h1c ready

    // ---- phase B: acc2 += h1c @ W2^T ----
    #pragma unroll
    for (int kh=0;kh<2;kh++){
      #pragma unroll
      for (int ksub=0;ksub<2;ksub++){
        bf16x8 af[2];
        #pragma unroll
        for (int rt=0;rt<2;rt++){
          int row = rgB*32 + rt*16 + (lane&15);
          int g0 = kh*8 + ksub*4 + (lane>>4);
          int gs = g0 ^ (row & 7);
          af[rt] = *(const bf16x8*)&h1c[row*128 + gs*8];
        }
        #pragma unroll
        for (int cth=0;cth<2;cth++){
          const unsigned short* wb = W2f + ((((nt*2 + kh)*2 + ksub)*32) + cgB*16 + cth*8)*512 + lane*8;
          bf16x8 bg[8];
          #pragma unroll
          for (int ct=0;ct<8;ct++) bg[ct] = *(const bf16x8*)(wb + ct*512);
          #pragma unroll
          for (int rt=0;rt<2;rt++)
            #pragma unroll
            for (int ct=0;ct<8;ct++)
              acc2[rt][cth*8+ct] = __builtin_amdgcn_mfma_f32_16x16x32_bf16(af[rt], bg[ct], acc2[rt][cth*8+ct], 0,0,0);
        }
      }
    }
    // no barrier here: next nt's first barrier orders h1c reads vs rewrite
  }

  // epilogue: Y2 bf16 store + BN2 stats
  #pragma unroll
  for (int ct=0;ct<16;ct++){
    int col = cgB*256 + ct*16 + (lane&15);
    float s = 0.f, q = 0.f;
    #pragma unroll
    for (int rt=0;rt<2;rt++)
      #pragma unroll
      for (int r=0;r<4;r++){
        long row = m0 + rgB*32 + rt*16 + (lane>>4)*4 + r;
        unsigned short ub = f2bf(acc2[rt][ct][r]);
        Y2[row*512 + col] = ub;
        float vq = bf2f(ub);
        s += vq; q += vq*vq;
      }
    s += __shfl_down(s, 32); q += __shfl_down(q, 32);
    s += __shfl_down(s, 16); q += __shfl_down(q, 16);
    if (lane < 16){
      atomicAdd(&bnsum[col], s);
      atomicAdd(&bnsq[col], q);
    }
  }
}

// ---------------- layer3 ----------------
__global__ __launch_bounds__(256) void final_kernel(
    const unsigned short* __restrict__ Y2,
    const float* __restrict__ a2, const float* __restrict__ c2,
    const float* __restrict__ W3, const float* __restrict__ b3, float* __restrict__ Q){
  const int tid = threadIdx.x;
  const int lane = tid & 63, wv = tid >> 6;
  const int wid = blockIdx.x*4 + wv;
  const int cb = lane*8;
  float4 a0 = *(const float4*)&a2[cb], a1 = *(const float4*)&a2[cb+4];
  float4 c0 = *(const float4*)&c2[cb], c1 = *(const float4*)&c2[cb+4];
  float4 w0 = *(const float4*)&W3[cb], w1 = *(const float4*)&W3[cb+4];
  const float b3v = b3[0];
  for (long row = wid; row < NROW; row += 4096){
    uint4 u = *(const uint4*)(Y2 + row*512 + cb);
    float y0 = bf2f(u.x & 0xffffu), y1 = bf2f(u.x >> 16);
    float y2 = bf2f(u.y & 0xffffu), y3 = bf2f(u.y >> 16);
    float y4 = bf2f(u.z & 0xffffu), y5 = bf2f(u.z >> 16);
    float y6 = bf2f(u.w & 0xffffu), y7 = bf2f(u.w >> 16);
    float t = fmaxf(fmaf(y0,a0.x,c0.x),0.f)*w0.x
            + fmaxf(fmaf(y1,a0.y,c0.y),0.f)*w0.y
            + fmaxf(fmaf(y2,a0.z,c0.z),0.f)*w0.z
            + fmaxf(fmaf(y3,a0.w,c0.w),0.f)*w0.w
            + fmaxf(fmaf(y4,a1.x,c1.x),0.f)*w1.x
            + fmaxf(fmaf(y5,a1.y,c1.y),0.f)*w1.y
            + fmaxf(fmaf(y6,a1.z,c1.z),0.f)*w1.z
            + fmaxf(fmaf(y7,a1.w,c1.w),0.f)*w1.w;
    #pragma unroll
    for (int off=32; off>=1; off>>=1) t += __shfl_down(t, off);
    if (lane == 0) Q[row] = t + b3v;
  }
}

// ---------------- launch ----------------
extern "C" void kernel_launch(void* const* d_in, const int* in_sizes, int n_in,
                              void* d_out, int out_size, void* d_ws, size_t ws_size,
                              hipStream_t stream){
  (void)in_sizes; (void)n_in; (void)out_size;
  if (ws_size < NEED2) return;   // proven to fit in round 2

  const float* state  = (const float*)d_in[0];
  const float* action = (const float*)d_in[1];
  const float* w_ih_f = (const float*)d_in[2];
  const float* w_hh_f = (const float*)d_in[3];
  const float* b_ih_f = (const float*)d_in[4];
  const float* b_hh_f = (const float*)d_in[5];
  const float* w_ih_r = (const float*)d_in[6];
  const float* w_hh_r = (const float*)d_in[7];
  const float* b_ih_r = (const float*)d_in[8];
  const float* b_hh_r = (const float*)d_in[9];
  const float* W1  = (const float*)d_in[10];
  const float* b1  = (const float*)d_in[11];
  const float* g1  = (const float*)d_in[12];
  const float* be1 = (const float*)d_in[13];
  const float* W2  = (const float*)d_in[14];
  const float* b2  = (const float*)d_in[15];
  const float* g2  = (const float*)d_in[16];
  const float* be2 = (const float*)d_in[17];
  const float* W3  = (const float*)d_in[18];
  const float* b3  = (const float*)d_in[19];
  (void)b1; (void)b2;  // cancel inside BatchNorm

  char* ws = (char*)d_ws;
  unsigned short* XOA = (unsigned short*)(ws + WS_XOA);
  unsigned short* Y2  = (unsigned short*)(ws + WS_Y2);
  float* Ysp = (float*)(ws + WS_YS);
  char* sm = ws + WS_SM;
  unsigned short* W1f = (unsigned short*)(sm + SM_W1F);
  unsigned short* W2f = (unsigned short*)(sm + SM_W2F);
  unsigned short* wih = (unsigned short*)(sm + SM_WIH);
  unsigned short* whh = (unsigned short*)(sm + SM_WHH);
  float* bias   = (float*)(sm + SM_BIAS);
  float* bnsum1 = (float*)(sm + SM_STAT);
  float* bnsq1  = (float*)(sm + SM_STAT + 0x1000);
  float* bnsum2 = (float*)(sm + SM_STAT + 0x2000);
  float* bnsq2  = (float*)(sm + SM_STAT + 0x2800);
  float* a1 = (float*)(sm + SM_A1);
  float* c1 = (float*)(sm + SM_C1);
  float* a2 = (float*)(sm + SM_A2);
  float* c2 = (float*)(sm + SM_C2);
  float* qout = (float*)d_out;
  float* regout = qout + 131072;

  hipMemsetAsync(bnsum1, 0, 0x3000, stream);
  hipMemsetAsync(regout, 0, 4, stream);

  prep_kernel<<<1024, 256, 0, stream>>>(w_ih_f, w_hh_f, b_ih_f, b_hh_f,
                                        w_ih_r, w_hh_r, b_ih_r, b_hh_r,
                                        W1, W2, W1f, W2f, wih, whh, bias);
  reg_kernel<<<256, 256, 0, stream>>>(w_ih_f, w_hh_f, b_ih_f, b_hh_f,
                                      w_ih_r, w_hh_r, b_ih_r, b_hh_r,
                                      W1, b1, g1, be1, W2, b2, g2, be2, W3, b3, regout);
  ys_kernel<<<dim3(32, 8), 256, 0, stream>>>(state, W1f, Ysp);
  lstm_kernel<<<dim3(128,2), 256, 0, stream>>>(action, wih, whh, bias, XOA);
  attn_pack<<<4096, 256, 0, stream>>>(action, XOA);
  gemm1_stats<<<2048, 256, 0, stream>>>(action, XOA, W1f, Ysp, bnsum1, bnsq1);
  bn_finalize<<<4, 256, 0, stream>>>(bnsum1, bnsq1, g1, be1, a1, c1, 1024);
  gemm12<<<2048, 256, 0, stream>>>(action, XOA, W1f, W2f, Ysp, a1, c1, Y2, bnsum2, bnsq2);
  bn_finalize<<<2, 256, 0, stream>>>(bnsum2, bnsq2, g2, be2, a2, c2, 512);
  final_kernel<<<1024, 256, 0, stream>>>(Y2, a2, c2, W3, b3, qout);
}